// Round 1
// baseline (1388.142 us; speedup 1.0000x reference)
//
#include <hip/hip_runtime.h>
#include <hip/hip_bf16.h>
#include <math.h>

// ---------------- problem constants ----------------
#define TT     1024      // T
#define METAN  6
#define TT1    1030      // T + META
#define BB     2
#define DD     512
#define HH     8
#define HSZ    64
#define LL     6
#define NVOCAB 32000
#define MROWS  2060      // B*T1
#define MPAD   2176      // 17 * 128 (padded row count for 128-tiles)
#define SCALE  0.044194173824159216f   // 512^-0.5

typedef float  f32x4  __attribute__((ext_vector_type(4)));
typedef __bf16 bf16x8 __attribute__((ext_vector_type(8)));

__device__ __forceinline__ __bf16 f2bf(float f) {
  unsigned int u = __builtin_bit_cast(unsigned int, f);
  u = u + 0x7FFFu + ((u >> 16) & 1u);           // RNE
  unsigned short h = (unsigned short)(u >> 16);
  return __builtin_bit_cast(__bf16, h);
}

// ---------------- embedding + positional encoding ----------------
// grid: MROWS blocks, 128 threads; each thread does 4 floats of D=512.
__global__ void k_embed(const int* __restrict__ idx, const int* __restrict__ midx,
                        const float* __restrict__ tok, const float* __restrict__ met,
                        float* __restrict__ x)
{
  int row = blockIdx.x;
  int b = row / TT1, t = row - b * TT1;
  int d0 = threadIdx.x * 4;
  float v[4];
  if (t < TT) {
    const float* e = tok + (size_t)idx[b * TT + t] * DD;
    float pos = (float)(t / 6);
#pragma unroll
    for (int j = 0; j < 4; j += 2) {
      int i = (d0 + j) >> 1;
      float dv = expf((float)i * (-2.0f * 9.210340371976184f / 512.0f));
      float ang = pos * dv;
      v[j]     = e[d0 + j]     + sinf(ang);
      v[j + 1] = e[d0 + j + 1] + cosf(ang);
    }
  } else {
    const float* e = met + (size_t)midx[b * METAN + (t - TT)] * DD;
#pragma unroll
    for (int j = 0; j < 4; j++) v[j] = e[d0 + j];
  }
  *(float4*)&x[(size_t)row * DD + d0] = *(float4*)v;
}

// ---------------- layernorm (fp32 in, bf16 out) ----------------
// block (64,4): one wave per row, 8 floats/lane.
__global__ void k_ln(const float* __restrict__ x, const float* __restrict__ g,
                     const float* __restrict__ be, __bf16* __restrict__ o)
{
  int row = blockIdx.x * 4 + threadIdx.y;
  int lane = threadIdx.x;
  const float* xr = x + (size_t)row * DD;
  float v[8];
  *(float4*)&v[0] = *(const float4*)&xr[lane * 8];
  *(float4*)&v[4] = *(const float4*)&xr[lane * 8 + 4];
  float s = 0.f;
#pragma unroll
  for (int j = 0; j < 8; j++) s += v[j];
#pragma unroll
  for (int msk = 1; msk < 64; msk <<= 1) s += __shfl_xor(s, msk);
  float mu = s * (1.0f / 512.0f);
  float q = 0.f;
#pragma unroll
  for (int j = 0; j < 8; j++) { v[j] -= mu; q += v[j] * v[j]; }
#pragma unroll
  for (int msk = 1; msk < 64; msk <<= 1) q += __shfl_xor(q, msk);
  float rs = rsqrtf(q * (1.0f / 512.0f) + 1e-5f);
  float4 g0 = *(const float4*)&g[lane * 8], g1 = *(const float4*)&g[lane * 8 + 4];
  float4 b0 = *(const float4*)&be[lane * 8], b1 = *(const float4*)&be[lane * 8 + 4];
  float gg[8] = {g0.x, g0.y, g0.z, g0.w, g1.x, g1.y, g1.z, g1.w};
  float bb[8] = {b0.x, b0.y, b0.z, b0.w, b1.x, b1.y, b1.z, b1.w};
  __bf16 ov[8];
#pragma unroll
  for (int j = 0; j < 8; j++) ov[j] = f2bf(v[j] * rs * gg[j] + bb[j]);
  *(bf16x8*)&o[(size_t)row * DD + lane * 8] = *(bf16x8*)ov;
}

// ---------------- transpose + fp32->bf16 weight conversion ----------------
// in: [batch][R][C] fp32  ->  out: per-batch [C][R] bf16 at
//   out + (b/lo_cnt)*bs_hi + (b%lo_cnt)*bs_lo.  R,C multiples of 32.
__global__ void k_tcvt(const float* __restrict__ in, __bf16* __restrict__ out,
                       int R, int C, long long in_bs,
                       long long bs_hi, long long bs_lo, int lo_cnt)
{
  __shared__ float t[32][33];
  int bb = blockIdx.z;
  const float* ib = in + (long long)bb * in_bs;
  __bf16* ob = out + (long long)(bb / lo_cnt) * bs_hi + (long long)(bb % lo_cnt) * bs_lo;
  int c = blockIdx.x * 32 + threadIdx.x;
  for (int j = threadIdx.y; j < 32; j += 8)
    t[j][threadIdx.x] = ib[(size_t)(blockIdx.y * 32 + j) * C + c];
  __syncthreads();
  int r = blockIdx.y * 32 + threadIdx.x;
  for (int j = threadIdx.y; j < 32; j += 8)
    ob[(size_t)(blockIdx.x * 32 + j) * R + r] = f2bf(t[threadIdx.x][j]);
}

// ---------------- generic bf16 GEMM:  C[M,N] = A[M,K] * Bt[N,K]^T ----------------
// 128x128 tile, BK=32, 4 waves (2x2), 16x16x32 MFMA, XOR-swizzled LDS.
// MODE 0: outb[row*N+col] = bf16(acc (+bias) (ReLU))
// MODE 1: outf[row*N+col] = res[row*N+col] + acc + bias   (residual, in-place ok)
// MODE 2: LM head: row=(b,t), t<1024 only: outf[(b*1024+t)*N+col] = acc + bias
template <int MODE, bool RELU, bool BIAS>
__global__ __launch_bounds__(256) void k_gemm(
    const __bf16* __restrict__ A, const __bf16* __restrict__ Bt,
    const float* __restrict__ bias, const float* __restrict__ res,
    float* __restrict__ outf, __bf16* __restrict__ outb,
    int M, int N, int K)
{
  __shared__ __align__(16) __bf16 As[4096];   // 128 x 32
  __shared__ __align__(16) __bf16 Bs[4096];
  const int tid = threadIdx.x;
  const int lane = tid & 63, w = tid >> 6;
  const int wm = w >> 1, wn = w & 1;
  const int rm = lane & 15, g4 = lane >> 4;
  const int row0 = blockIdx.x * 128, col0 = blockIdx.y * 128;

  f32x4 acc[4][4];
  const f32x4 fz = {0.f, 0.f, 0.f, 0.f};
#pragma unroll
  for (int i = 0; i < 4; i++)
#pragma unroll
    for (int j = 0; j < 4; j++) acc[i][j] = fz;

  const int srow = tid >> 2, skc = tid & 3;
  const __bf16* Ag = A + (size_t)(row0 + srow) * K + skc * 8;
  const __bf16* Bg = Bt + (size_t)(col0 + srow) * K + skc * 8;
  const int wA0 = (((srow * 4 + skc) ^ (srow & 7)) * 8);
  const int wA1 = ((((srow + 64) * 4 + skc) ^ (srow & 7)) * 8);

  for (int k0 = 0; k0 < K; k0 += 32) {
    bf16x8 a0 = *(const bf16x8*)(Ag + k0);
    bf16x8 a1 = *(const bf16x8*)(Ag + (size_t)64 * K + k0);
    bf16x8 b0 = *(const bf16x8*)(Bg + k0);
    bf16x8 b1 = *(const bf16x8*)(Bg + (size_t)64 * K + k0);
    __syncthreads();                 // previous iter's frag reads done
    *(bf16x8*)&As[wA0] = a0;
    *(bf16x8*)&As[wA1] = a1;
    *(bf16x8*)&Bs[wA0] = b0;
    *(bf16x8*)&Bs[wA1] = b1;
    __syncthreads();
    bf16x8 af[4], bfr[4];
#pragma unroll
    for (int m = 0; m < 4; m++) {
      int r = wm * 64 + m * 16 + rm;
      af[m] = *(const bf16x8*)&As[((r * 4 + g4) ^ (r & 7)) * 8];
    }
#pragma unroll
    for (int n = 0; n < 4; n++) {
      int r = wn * 64 + n * 16 + rm;
      bfr[n] = *(const bf16x8*)&Bs[((r * 4 + g4) ^ (r & 7)) * 8];
    }
#pragma unroll
    for (int m = 0; m < 4; m++)
#pragma unroll
      for (int n = 0; n < 4; n++)
        acc[m][n] = __builtin_amdgcn_mfma_f32_16x16x32_bf16(af[m], bfr[n], acc[m][n], 0, 0, 0);
  }

#pragma unroll
  for (int m = 0; m < 4; m++) {
    int row_b = row0 + wm * 64 + m * 16 + g4 * 4;
#pragma unroll
    for (int n = 0; n < 4; n++) {
      int col = col0 + wn * 64 + n * 16 + rm;
      float bv = BIAS ? bias[col] : 0.f;
#pragma unroll
      for (int r = 0; r < 4; r++) {
        int row = row_b + r;
        if (row >= M) continue;
        float v = acc[m][n][r] + bv;
        if (MODE == 0) {
          if (RELU) v = fmaxf(v, 0.f);
          outb[(size_t)row * N + col] = f2bf(v);
        } else if (MODE == 1) {
          outf[(size_t)row * N + col] = res[(size_t)row * N + col] + v;
        } else {
          int b = row / TT1, t = row - b * TT1;
          if (t < TT) outf[((size_t)(b * TT + t)) * N + col] = v;
        }
      }
    }
  }
}

// ---------------- fused masked attention (flash-style) ----------------
// qkv rows: [MPAD][1536] bf16, cols 0:512=Q, 512:1024=K, 1024:1536=V (n = h*64+e)
// grid (17, H, B); 4 waves; each wave owns 16 query rows; K/V tiles of 32.
__global__ __launch_bounds__(256) void k_attn(const __bf16* __restrict__ qkv,
                                              __bf16* __restrict__ ob)
{
  __shared__ __align__(16) __bf16 Ks[32][72];
  __shared__ __align__(16) __bf16 Vs[64][40];
  __shared__ __align__(16) __bf16 Ps[4][16][40];

  const int tid = threadIdx.x;
  const int lane = tid & 63, w = tid >> 6;
  const int rm = lane & 15, g4 = lane >> 4;
  const int q0 = blockIdx.x * 64;
  const int h = blockIdx.y, b = blockIdx.z;
  const int qw = q0 + w * 16;

  const size_t rs = 1536;
  const __bf16* qb = qkv + (size_t)b * TT1 * rs + h * HSZ;
  const __bf16* kb = qb + 512;
  const __bf16* vb = qb + 1024;

  bf16x8 aq[2];
  {
    const __bf16* qp = qb + (size_t)(qw + rm) * rs + 8 * g4;
    aq[0] = *(const bf16x8*)qp;
    aq[1] = *(const bf16x8*)(qp + 32);
  }

  int ae_[4];
#pragma unroll
  for (int r = 0; r < 4; r++) {
    int qr = qw + g4 * 4 + r;
    ae_[r] = (qr / 6 + 1) * 6;                 // chunked-causal limit
  }

  float m_[4], l_[4];
  f32x4 accO[4];
  const f32x4 fz = {0.f, 0.f, 0.f, 0.f};
#pragma unroll
  for (int j = 0; j < 4; j++) accO[j] = fz;
#pragma unroll
  for (int r = 0; r < 4; r++) { m_[r] = -1e30f; l_[r] = 0.f; }

  int aemax = ((q0 + 63) / 6 + 1) * 6;
  if (aemax > TT) aemax = TT;
  const int ntile = (aemax + 31) >> 5;         // main tiles cover [0, ntile*32) < 1024

  const int skey = tid >> 3;
  const int shs = (tid & 7) * 8;

  for (int tt = 0; tt <= ntile; ++tt) {
    const bool meta = (tt == ntile);
    const int kt = meta ? TT : tt * 32;        // metadata tile at kt=1024

    bf16x8 kv_k = *(const bf16x8*)(kb + (size_t)(kt + skey) * rs + shs);
    bf16x8 kv_v = *(const bf16x8*)(vb + (size_t)(kt + skey) * rs + shs);
    __syncthreads();
    *(bf16x8*)&Ks[skey][shs] = kv_k;
#pragma unroll
    for (int j = 0; j < 8; j++) Vs[shs + j][skey] = kv_v[j];
    __syncthreads();

    // S = Q K^T  (16 q x 32 keys per wave)
    f32x4 s[2];
#pragma unroll
    for (int nt = 0; nt < 2; nt++) {
      f32x4 a = fz;
      bf16x8 bk0 = *(const bf16x8*)&Ks[nt * 16 + rm][8 * g4];
      bf16x8 bk1 = *(const bf16x8*)&Ks[nt * 16 + rm][32 + 8 * g4];
      a = __builtin_amdgcn_mfma_f32_16x16x32_bf16(aq[0], bk0, a, 0, 0, 0);
      a = __builtin_amdgcn_mfma_f32_16x16x32_bf16(aq[1], bk1, a, 0, 0, 0);
      s[nt] = a;
    }

    float alpha[4];
#pragma unroll
    for (int r = 0; r < 4; r++) {
      float s0 = s[0][r] * SCALE;
      float s1 = s[1][r] * SCALE;
      int col0 = kt + rm;
      int lim = meta ? TT1 : ae_[r];
      if (col0 >= lim) s0 = -1e30f;
      if (col0 + 16 >= lim) s1 = -1e30f;
      float tm = fmaxf(s0, s1);
#pragma unroll
      for (int msk = 1; msk < 16; msk <<= 1) tm = fmaxf(tm, __shfl_xor(tm, msk));
      float mn = fmaxf(m_[r], tm);
      float p0 = __expf(s0 - mn);
      float p1 = __expf(s1 - mn);
      float ts = p0 + p1;
#pragma unroll
      for (int msk = 1; msk < 16; msk <<= 1) ts += __shfl_xor(ts, msk);
      alpha[r] = __expf(m_[r] - mn);
      l_[r] = l_[r] * alpha[r] + ts;
      m_[r] = mn;
      Ps[w][g4 * 4 + r][rm]      = f2bf(p0);
      Ps[w][g4 * 4 + r][rm + 16] = f2bf(p1);
    }
#pragma unroll
    for (int j = 0; j < 4; j++)
#pragma unroll
      for (int r = 0; r < 4; r++) accO[j][r] *= alpha[r];
    __syncthreads();                            // P visible to whole block

    bf16x8 pa = *(const bf16x8*)&Ps[w][rm][8 * g4];
#pragma unroll
    for (int j = 0; j < 4; j++) {
      bf16x8 bv = *(const bf16x8*)&Vs[j * 16 + rm][8 * g4];
      accO[j] = __builtin_amdgcn_mfma_f32_16x16x32_bf16(pa, bv, accO[j], 0, 0, 0);
    }
  }

#pragma unroll
  for (int r = 0; r < 4; r++) {
    int q = qw + g4 * 4 + r;
    if (q < TT1) {
      float rl = 1.0f / l_[r];
#pragma unroll
      for (int j = 0; j < 4; j++)
        ob[((size_t)b * TT1 + q) * DD + h * HSZ + j * 16 + rm] = f2bf(accO[j][r] * rl);
    }
  }
}

// ---------------- host launcher ----------------
extern "C" void kernel_launch(void* const* d_in, const int* in_sizes, int n_in,
                              void* d_out, int out_size, void* d_ws, size_t ws_size,
                              hipStream_t stream)
{
  const int*   idx   = (const int*)d_in[0];
  const int*   midx  = (const int*)d_in[1];
  const float* tok   = (const float*)d_in[2];
  const float* metae = (const float*)d_in[3];
  const float* Wq    = (const float*)d_in[4];
  const float* Wk    = (const float*)d_in[5];
  const float* Wv    = (const float*)d_in[6];
  const float* Wo    = (const float*)d_in[7];
  const float* bo    = (const float*)d_in[8];
  const float* W1    = (const float*)d_in[9];
  const float* b1    = (const float*)d_in[10];
  const float* W2    = (const float*)d_in[11];
  const float* b2    = (const float*)d_in[12];
  const float* ln1g  = (const float*)d_in[13];
  const float* ln1b  = (const float*)d_in[14];
  const float* ln2g  = (const float*)d_in[15];
  const float* ln2b  = (const float*)d_in[16];
  const float* lnfg  = (const float*)d_in[17];
  const float* lnfb  = (const float*)d_in[18];
  const float* Wlm   = (const float*)d_in[19];
  const float* blm   = (const float*)d_in[20];
  float* out = (float*)d_out;

  // workspace carve-up (~93 MB total)
  char* p = (char*)d_ws;
  auto alloc = [&](size_t bytes) { void* r = (void*)p; p += (bytes + 255) & ~(size_t)255; return r; };
  float*  x     = (float*)alloc((size_t)MPAD * 512 * 4);
  __bf16* hb    = (__bf16*)alloc((size_t)MPAD * 512 * 2);
  __bf16* qkv   = (__bf16*)alloc((size_t)MPAD * 1536 * 2);
  __bf16* obuf  = (__bf16*)alloc((size_t)MPAD * 512 * 2);
  __bf16* f1    = (__bf16*)alloc((size_t)MPAD * 2048 * 2);
  __bf16* xf    = (__bf16*)alloc((size_t)MPAD * 512 * 2);
  __bf16* wqkvb = (__bf16*)alloc((size_t)6 * 1536 * 512 * 2);
  __bf16* wob   = (__bf16*)alloc((size_t)6 * 512 * 512 * 2);
  __bf16* w1b   = (__bf16*)alloc((size_t)6 * 2048 * 512 * 2);
  __bf16* w2b   = (__bf16*)alloc((size_t)6 * 512 * 2048 * 2);
  __bf16* wlmb  = (__bf16*)alloc((size_t)NVOCAB * 512 * 2);
  (void)in_sizes; (void)n_in; (void)out_size; (void)ws_size;

  // weight conversion: fp32 -> bf16, transposed to [N][K]
  dim3 tcb(32, 8);
  k_tcvt<<<dim3(2, 16, 48), tcb, 0, stream>>>(Wq, wqkvb,          512, 64,   32768LL,  786432LL, 32768LL, 8);
  k_tcvt<<<dim3(2, 16, 48), tcb, 0, stream>>>(Wk, wqkvb + 262144, 512, 64,   32768LL,  786432LL, 32768LL, 8);
  k_tcvt<<<dim3(2, 16, 48), tcb, 0, stream>>>(Wv, wqkvb + 524288, 512, 64,   32768LL,  786432LL, 32768LL, 8);
  k_tcvt<<<dim3(16, 16, 6), tcb, 0, stream>>>(Wo, wob,  512, 512,  262144LL,  262144LL, 0LL, 1);
  k_tcvt<<<dim3(64, 16, 6), tcb, 0, stream>>>(W1, w1b,  512, 2048, 1048576LL, 1048576LL, 0LL, 1);
  k_tcvt<<<dim3(16, 64, 6), tcb, 0, stream>>>(W2, w2b,  2048, 512, 1048576LL, 1048576LL, 0LL, 1);
  k_tcvt<<<dim3(1000, 16, 1), tcb, 0, stream>>>(Wlm, wlmb, 512, 32000, 0LL, 0LL, 0LL, 1);

  k_embed<<<dim3(MROWS), dim3(128), 0, stream>>>(idx, midx, tok, metae, x);

  for (int l = 0; l < LL; ++l) {
    k_ln<<<dim3(515), dim3(64, 4), 0, stream>>>(x, ln1g + l * 512, ln1b + l * 512, hb);
    k_gemm<0, false, false><<<dim3(17, 12), 256, 0, stream>>>(
        hb, wqkvb + (size_t)l * 786432, nullptr, nullptr, nullptr, qkv, MROWS, 1536, 512);
    k_attn<<<dim3(17, 8, 2), 256, 0, stream>>>(qkv, obuf);
    k_gemm<1, false, true><<<dim3(17, 4), 256, 0, stream>>>(
        obuf, wob + (size_t)l * 262144, bo + l * 512, x, x, nullptr, MROWS, 512, 512);
    k_ln<<<dim3(515), dim3(64, 4), 0, stream>>>(x, ln2g + l * 512, ln2b + l * 512, hb);
    k_gemm<0, true, true><<<dim3(17, 16), 256, 0, stream>>>(
        hb, w1b + (size_t)l * 1048576, b1 + l * 2048, nullptr, nullptr, f1, MROWS, 2048, 512);
    k_gemm<1, false, true><<<dim3(17, 4), 256, 0, stream>>>(
        f1, w2b + (size_t)l * 1048576, b2 + l * 512, x, x, nullptr, MROWS, 512, 2048);
  }

  k_ln<<<dim3(515), dim3(64, 4), 0, stream>>>(x, lnfg, lnfb, xf);
  k_gemm<2, false, true><<<dim3(17, 250), 256, 0, stream>>>(
      xf, wlmb, blm, nullptr, out, nullptr, MROWS, NVOCAB, 512);
}

// Round 2
// 1339.242 us; speedup vs baseline: 1.0365x; 1.0365x over previous
//
#include <hip/hip_runtime.h>
#include <hip/hip_bf16.h>
#include <math.h>

// ---------------- problem constants ----------------
#define TT     1024      // T
#define METAN  6
#define TT1    1030      // T + META
#define BB     2
#define DD     512
#define HH     8
#define HSZ    64
#define LL     6
#define NVOCAB 32000
#define MROWS  2060      // B*T1
#define MPAD   2176      // 17 * 128 (padded row count for 128-tiles)
#define SCALE  0.044194173824159216f   // 512^-0.5

typedef float  f32x4  __attribute__((ext_vector_type(4)));
typedef __bf16 bf16x8 __attribute__((ext_vector_type(8)));

__device__ __forceinline__ __bf16 f2bf(float f) {
  unsigned int u = __builtin_bit_cast(unsigned int, f);
  u = u + 0x7FFFu + ((u >> 16) & 1u);           // RNE
  unsigned short h = (unsigned short)(u >> 16);
  return __builtin_bit_cast(__bf16, h);
}

__device__ __forceinline__ int lmrow(int r) {   // compact LM row -> x row
  return (r >> 10) * TT1 + (r & 1023);
}

// normalize 8 fp32 -> bf16x8:  (v - mu) * rs * g + b
__device__ __forceinline__ bf16x8 ln8(const float* __restrict__ xp, float mu, float rs,
                                      const float* __restrict__ g, const float* __restrict__ b) {
  float4 v0 = *(const float4*)xp,     v1 = *(const float4*)(xp + 4);
  float4 g0 = *(const float4*)g,      g1 = *(const float4*)(g + 4);
  float4 b0 = *(const float4*)b,      b1 = *(const float4*)(b + 4);
  float vv[8] = {v0.x, v0.y, v0.z, v0.w, v1.x, v1.y, v1.z, v1.w};
  float gg[8] = {g0.x, g0.y, g0.z, g0.w, g1.x, g1.y, g1.z, g1.w};
  float bb[8] = {b0.x, b0.y, b0.z, b0.w, b1.x, b1.y, b1.z, b1.w};
  bf16x8 r;
#pragma unroll
  for (int j = 0; j < 8; j++) r[j] = f2bf((vv[j] - mu) * rs * gg[j] + bb[j]);
  return r;
}

// ---------------- embedding + positional encoding ----------------
__global__ void k_embed(const int* __restrict__ idx, const int* __restrict__ midx,
                        const float* __restrict__ tok, const float* __restrict__ met,
                        float* __restrict__ x)
{
  int row = blockIdx.x;
  int b = row / TT1, t = row - b * TT1;
  int d0 = threadIdx.x * 4;
  float v[4];
  if (t < TT) {
    const float* e = tok + (size_t)idx[b * TT + t] * DD;
    float pos = (float)(t / 6);
#pragma unroll
    for (int j = 0; j < 4; j += 2) {
      int i = (d0 + j) >> 1;
      float dv = expf((float)i * (-2.0f * 9.210340371976184f / 512.0f));
      float ang = pos * dv;
      v[j]     = e[d0 + j]     + sinf(ang);
      v[j + 1] = e[d0 + j + 1] + cosf(ang);
    }
  } else {
    const float* e = met + (size_t)midx[b * METAN + (t - TT)] * DD;
#pragma unroll
    for (int j = 0; j < 4; j++) v[j] = e[d0 + j];
  }
  *(float4*)&x[(size_t)row * DD + d0] = *(float4*)v;
}

// ---------------- per-row LN stats: mu, 1/sigma ----------------
// block (64,4): one wave per row.
__global__ void k_rowstat(const float* __restrict__ x, float* __restrict__ mu,
                          float* __restrict__ rs)
{
  int row = blockIdx.x * 4 + threadIdx.y;
  int lane = threadIdx.x;
  const float* xr = x + (size_t)row * DD;
  float v[8];
  *(float4*)&v[0] = *(const float4*)&xr[lane * 8];
  *(float4*)&v[4] = *(const float4*)&xr[lane * 8 + 4];
  float s = 0.f;
#pragma unroll
  for (int j = 0; j < 8; j++) s += v[j];
#pragma unroll
  for (int msk = 1; msk < 64; msk <<= 1) s += __shfl_xor(s, msk);
  float m = s * (1.0f / 512.0f);
  float q = 0.f;
#pragma unroll
  for (int j = 0; j < 8; j++) { float d = v[j] - m; q += d * d; }
#pragma unroll
  for (int msk = 1; msk < 64; msk <<= 1) q += __shfl_xor(q, msk);
  if (lane == 0) {
    mu[row] = m;
    rs[row] = rsqrtf(q * (1.0f / 512.0f) + 1e-5f);
  }
}

// ---------------- transpose + fp32->bf16 weight conversion ----------------
__global__ void k_tcvt(const float* __restrict__ in, __bf16* __restrict__ out,
                       int R, int C, long long in_bs,
                       long long bs_hi, long long bs_lo, int lo_cnt)
{
  __shared__ float t[32][33];
  int bb = blockIdx.z;
  const float* ib = in + (long long)bb * in_bs;
  __bf16* ob = out + (long long)(bb / lo_cnt) * bs_hi + (long long)(bb % lo_cnt) * bs_lo;
  int c = blockIdx.x * 32 + threadIdx.x;
  for (int j = threadIdx.y; j < 32; j += 8)
    t[j][threadIdx.x] = ib[(size_t)(blockIdx.y * 32 + j) * C + c];
  __syncthreads();
  int r = blockIdx.y * 32 + threadIdx.x;
  for (int j = threadIdx.y; j < 32; j += 8)
    ob[(size_t)(blockIdx.x * 32 + j) * R + r] = f2bf(t[threadIdx.x][j]);
}

// ---------------- generic bf16 GEMM:  C[M,NT-tile] = A[M,K] * Bt[N,K]^T ----------------
// M-tile 128, N-tile NT (128: 4 waves 2x2; 64: 4 waves 4x1), BK=32, XOR-swizzled LDS.
// AMODE 0: A is bf16 [.][K].   AMODE 1: A = layernorm(Ax fp32 row) on the fly (K==512).
// MODE 0: outb = bf16(acc (+bias) (ReLU))
// MODE 1: outf = res + acc + bias   (residual, in-place ok)
// MODE 2: outf = acc + bias (LM head, COMPACT rows)
template <int MODE, bool RELU, bool BIAS, int AMODE, int NT, bool COMPACT>
__global__ __launch_bounds__(256) void k_gemm(
    const __bf16* __restrict__ A, const float* __restrict__ Ax,
    const float* __restrict__ mu, const float* __restrict__ rs,
    const float* __restrict__ lng, const float* __restrict__ lnb,
    const __bf16* __restrict__ Bt, const float* __restrict__ bias,
    const float* __restrict__ res,
    float* __restrict__ outf, __bf16* __restrict__ outb,
    int M, int N, int K)
{
  __shared__ __align__(16) __bf16 As[4096];        // 128 x 32
  __shared__ __align__(16) __bf16 Bs[NT * 32];
  const int tid = threadIdx.x;
  const int lane = tid & 63, w = tid >> 6;
  const int wm = (NT == 128) ? (w >> 1) : w;
  const int wn = (NT == 128) ? (w & 1) : 0;
  const int MR = (NT == 128) ? 4 : 2;              // m-fragments per wave
  const int WMS = (NT == 128) ? 64 : 32;           // wave m stride
  const int rm = lane & 15, g4 = lane >> 4;

  // XCD-bijective swizzle: row-tile fastest within each XCD's contiguous chunk
  const int nbx = gridDim.x;
  int flat = blockIdx.y * nbx + blockIdx.x;
  {
    const int nwg = nbx * gridDim.y;
    const int q = nwg >> 3, rr = nwg & 7;
    const int xcd = flat & 7, ii = flat >> 3;
    flat = (xcd < rr ? xcd * (q + 1) : rr * (q + 1) + (xcd - rr) * q) + ii;
  }
  const int row0 = (flat % nbx) * 128;
  const int col0 = (flat / nbx) * NT;

  f32x4 acc[MR][4];
  const f32x4 fz = {0.f, 0.f, 0.f, 0.f};
#pragma unroll
  for (int i = 0; i < MR; i++)
#pragma unroll
    for (int j = 0; j < 4; j++) acc[i][j] = fz;

  const int srow = tid >> 2, skc = tid & 3;
  const int wA0 = (((srow * 4 + skc) ^ (srow & 7)) * 8);
  const int wA1 = ((((srow + 64) * 4 + skc) ^ (srow & 7)) * 8);

  // A staging pointers
  const __bf16* Ag = nullptr;
  const float *Ax0 = nullptr, *Ax1 = nullptr, *gk = nullptr, *bk = nullptr;
  float mu0 = 0.f, rs0 = 0.f, mu1 = 0.f, rs1 = 0.f;
  if (AMODE == 0) {
    Ag = A + (size_t)(row0 + srow) * K + skc * 8;
  } else {
    int ra0 = row0 + srow, ra1 = ra0 + 64;
    int sa0 = COMPACT ? lmrow(ra0) : ra0;
    int sa1 = COMPACT ? lmrow(ra1) : ra1;
    Ax0 = Ax + (size_t)sa0 * DD + skc * 8;
    Ax1 = Ax + (size_t)sa1 * DD + skc * 8;
    mu0 = mu[sa0]; rs0 = rs[sa0]; mu1 = mu[sa1]; rs1 = rs[sa1];
    gk = lng + skc * 8; bk = lnb + skc * 8;
  }
  const __bf16* Bg = Bt + (size_t)(col0 + srow) * K + skc * 8;

  for (int k0 = 0; k0 < K; k0 += 32) {
    bf16x8 a0, a1, b0, b1;
    if (AMODE == 0) {
      a0 = *(const bf16x8*)(Ag + k0);
      a1 = *(const bf16x8*)(Ag + (size_t)64 * K + k0);
    } else {
      a0 = ln8(Ax0 + k0, mu0, rs0, gk + k0, bk + k0);
      a1 = ln8(Ax1 + k0, mu1, rs1, gk + k0, bk + k0);
    }
    b0 = *(const bf16x8*)(Bg + k0);
    if (NT == 128) b1 = *(const bf16x8*)(Bg + (size_t)64 * K + k0);
    __syncthreads();                 // previous iter's frag reads done
    *(bf16x8*)&As[wA0] = a0;
    *(bf16x8*)&As[wA1] = a1;
    if (NT == 128) {
      *(bf16x8*)&Bs[wA0] = b0;
      *(bf16x8*)&Bs[wA1] = b1;
    } else {
      *(bf16x8*)&Bs[wA0] = b0;       // 256 chunks == 256 threads
    }
    __syncthreads();
    bf16x8 af[MR], bfr[4];
#pragma unroll
    for (int m = 0; m < MR; m++) {
      int r = wm * WMS + m * 16 + rm;
      af[m] = *(const bf16x8*)&As[((r * 4 + g4) ^ (r & 7)) * 8];
    }
#pragma unroll
    for (int n = 0; n < 4; n++) {
      int r = wn * 64 + n * 16 + rm;
      bfr[n] = *(const bf16x8*)&Bs[((r * 4 + g4) ^ (r & 7)) * 8];
    }
#pragma unroll
    for (int m = 0; m < MR; m++)
#pragma unroll
      for (int n = 0; n < 4; n++)
        acc[m][n] = __builtin_amdgcn_mfma_f32_16x16x32_bf16(af[m], bfr[n], acc[m][n], 0, 0, 0);
  }

#pragma unroll
  for (int m = 0; m < MR; m++) {
    int row_b = row0 + wm * WMS + m * 16 + g4 * 4;
#pragma unroll
    for (int n = 0; n < 4; n++) {
      int col = col0 + wn * 64 + n * 16 + rm;
      float bv = BIAS ? bias[col] : 0.f;
#pragma unroll
      for (int r = 0; r < 4; r++) {
        int row = row_b + r;
        if (row >= M) continue;
        float v = acc[m][n][r] + bv;
        if (MODE == 0) {
          if (RELU) v = fmaxf(v, 0.f);
          outb[(size_t)row * N + col] = f2bf(v);
        } else if (MODE == 1) {
          outf[(size_t)row * N + col] = res[(size_t)row * N + col] + v;
        } else {
          outf[(size_t)row * N + col] = v;   // COMPACT rows are output rows
        }
      }
    }
  }
}

// ---------------- fused masked attention (flash-style) ----------------
__global__ __launch_bounds__(256) void k_attn(const __bf16* __restrict__ qkv,
                                              __bf16* __restrict__ ob)
{
  __shared__ __align__(16) __bf16 Ks[32][72];
  __shared__ __align__(16) __bf16 Vs[64][40];
  __shared__ __align__(16) __bf16 Ps[4][16][40];

  const int tid = threadIdx.x;
  const int lane = tid & 63, w = tid >> 6;
  const int rm = lane & 15, g4 = lane >> 4;
  const int q0 = blockIdx.x * 64;
  const int h = blockIdx.y, b = blockIdx.z;
  const int qw = q0 + w * 16;

  const size_t rsd = 1536;
  const __bf16* qb = qkv + (size_t)b * TT1 * rsd + h * HSZ;
  const __bf16* kb = qb + 512;
  const __bf16* vb = qb + 1024;

  bf16x8 aq[2];
  {
    const __bf16* qp = qb + (size_t)(qw + rm) * rsd + 8 * g4;
    aq[0] = *(const bf16x8*)qp;
    aq[1] = *(const bf16x8*)(qp + 32);
  }

  int ae_[4];
#pragma unroll
  for (int r = 0; r < 4; r++) {
    int qr = qw + g4 * 4 + r;
    ae_[r] = (qr / 6 + 1) * 6;                 // chunked-causal limit
  }

  float m_[4], l_[4];
  f32x4 accO[4];
  const f32x4 fz = {0.f, 0.f, 0.f, 0.f};
#pragma unroll
  for (int j = 0; j < 4; j++) accO[j] = fz;
#pragma unroll
  for (int r = 0; r < 4; r++) { m_[r] = -1e30f; l_[r] = 0.f; }

  int aemax = ((q0 + 63) / 6 + 1) * 6;
  if (aemax > TT) aemax = TT;
  const int ntile = (aemax + 31) >> 5;

  const int skey = tid >> 3;
  const int shs = (tid & 7) * 8;

  for (int tt = 0; tt <= ntile; ++tt) {
    const bool meta = (tt == ntile);
    const int kt = meta ? TT : tt * 32;

    bf16x8 kv_k = *(const bf16x8*)(kb + (size_t)(kt + skey) * rsd + shs);
    bf16x8 kv_v = *(const bf16x8*)(vb + (size_t)(kt + skey) * rsd + shs);
    __syncthreads();
    *(bf16x8*)&Ks[skey][shs] = kv_k;
#pragma unroll
    for (int j = 0; j < 8; j++) Vs[shs + j][skey] = kv_v[j];
    __syncthreads();

    f32x4 s[2];
#pragma unroll
    for (int nt = 0; nt < 2; nt++) {
      f32x4 a = fz;
      bf16x8 bk0 = *(const bf16x8*)&Ks[nt * 16 + rm][8 * g4];
      bf16x8 bk1 = *(const bf16x8*)&Ks[nt * 16 + rm][32 + 8 * g4];
      a = __builtin_amdgcn_mfma_f32_16x16x32_bf16(aq[0], bk0, a, 0, 0, 0);
      a = __builtin_amdgcn_mfma_f32_16x16x32_bf16(aq[1], bk1, a, 0, 0, 0);
      s[nt] = a;
    }

    float alpha[4];
#pragma unroll
    for (int r = 0; r < 4; r++) {
      float s0 = s[0][r] * SCALE;
      float s1 = s[1][r] * SCALE;
      int col0k = kt + rm;
      int lim = meta ? TT1 : ae_[r];
      if (col0k >= lim) s0 = -1e30f;
      if (col0k + 16 >= lim) s1 = -1e30f;
      float tm = fmaxf(s0, s1);
#pragma unroll
      for (int msk = 1; msk < 16; msk <<= 1) tm = fmaxf(tm, __shfl_xor(tm, msk));
      float mn = fmaxf(m_[r], tm);
      float p0 = __expf(s0 - mn);
      float p1 = __expf(s1 - mn);
      float ts = p0 + p1;
#pragma unroll
      for (int msk = 1; msk < 16; msk <<= 1) ts += __shfl_xor(ts, msk);
      alpha[r] = __expf(m_[r] - mn);
      l_[r] = l_[r] * alpha[r] + ts;
      m_[r] = mn;
      Ps[w][g4 * 4 + r][rm]      = f2bf(p0);
      Ps[w][g4 * 4 + r][rm + 16] = f2bf(p1);
    }
#pragma unroll
    for (int j = 0; j < 4; j++)
#pragma unroll
      for (int r = 0; r < 4; r++) accO[j][r] *= alpha[r];
    __syncthreads();

    bf16x8 pa = *(const bf16x8*)&Ps[w][rm][8 * g4];
#pragma unroll
    for (int j = 0; j < 4; j++) {
      bf16x8 bv = *(const bf16x8*)&Vs[j * 16 + rm][8 * g4];
      accO[j] = __builtin_amdgcn_mfma_f32_16x16x32_bf16(pa, bv, accO[j], 0, 0, 0);
    }
  }

#pragma unroll
  for (int r = 0; r < 4; r++) {
    int q = qw + g4 * 4 + r;
    if (q < TT1) {
      float rl = 1.0f / l_[r];
#pragma unroll
      for (int j = 0; j < 4; j++)
        ob[((size_t)b * TT1 + q) * DD + h * HSZ + j * 16 + rm] = f2bf(accO[j][r] * rl);
    }
  }
}

// ---------------- host launcher ----------------
extern "C" void kernel_launch(void* const* d_in, const int* in_sizes, int n_in,
                              void* d_out, int out_size, void* d_ws, size_t ws_size,
                              hipStream_t stream)
{
  const int*   idx   = (const int*)d_in[0];
  const int*   midx  = (const int*)d_in[1];
  const float* tok   = (const float*)d_in[2];
  const float* metae = (const float*)d_in[3];
  const float* Wq    = (const float*)d_in[4];
  const float* Wk    = (const float*)d_in[5];
  const float* Wv    = (const float*)d_in[6];
  const float* Wo    = (const float*)d_in[7];
  const float* bo    = (const float*)d_in[8];
  const float* W1    = (const float*)d_in[9];
  const float* b1    = (const float*)d_in[10];
  const float* W2    = (const float*)d_in[11];
  const float* b2    = (const float*)d_in[12];
  const float* ln1g  = (const float*)d_in[13];
  const float* ln1b  = (const float*)d_in[14];
  const float* ln2g  = (const float*)d_in[15];
  const float* ln2b  = (const float*)d_in[16];
  const float* lnfg  = (const float*)d_in[17];
  const float* lnfb  = (const float*)d_in[18];
  const float* Wlm   = (const float*)d_in[19];
  const float* blm   = (const float*)d_in[20];
  float* out = (float*)d_out;

  char* p = (char*)d_ws;
  auto alloc = [&](size_t bytes) { void* r = (void*)p; p += (bytes + 255) & ~(size_t)255; return r; };
  float*  x     = (float*)alloc((size_t)MPAD * 512 * 4);
  float*  mu_   = (float*)alloc((size_t)MPAD * 4);
  float*  rs_   = (float*)alloc((size_t)MPAD * 4);
  __bf16* qkv   = (__bf16*)alloc((size_t)MPAD * 1536 * 2);
  __bf16* obuf  = (__bf16*)alloc((size_t)MPAD * 512 * 2);
  __bf16* f1    = (__bf16*)alloc((size_t)MPAD * 2048 * 2);
  __bf16* wqkvb = (__bf16*)alloc((size_t)6 * 1536 * 512 * 2);
  __bf16* wob   = (__bf16*)alloc((size_t)6 * 512 * 512 * 2);
  __bf16* w1b   = (__bf16*)alloc((size_t)6 * 2048 * 512 * 2);
  __bf16* w2b   = (__bf16*)alloc((size_t)6 * 512 * 2048 * 2);
  __bf16* wlmb  = (__bf16*)alloc((size_t)NVOCAB * 512 * 2);
  (void)in_sizes; (void)n_in; (void)out_size; (void)ws_size;

  dim3 tcb(32, 8);
  k_tcvt<<<dim3(2, 16, 48), tcb, 0, stream>>>(Wq, wqkvb,          512, 64,   32768LL,  786432LL, 32768LL, 8);
  k_tcvt<<<dim3(2, 16, 48), tcb, 0, stream>>>(Wk, wqkvb + 262144, 512, 64,   32768LL,  786432LL, 32768LL, 8);
  k_tcvt<<<dim3(2, 16, 48), tcb, 0, stream>>>(Wv, wqkvb + 524288, 512, 64,   32768LL,  786432LL, 32768LL, 8);
  k_tcvt<<<dim3(16, 16, 6), tcb, 0, stream>>>(Wo, wob,  512, 512,  262144LL,  262144LL, 0LL, 1);
  k_tcvt<<<dim3(64, 16, 6), tcb, 0, stream>>>(W1, w1b,  512, 2048, 1048576LL, 1048576LL, 0LL, 1);
  k_tcvt<<<dim3(16, 64, 6), tcb, 0, stream>>>(W2, w2b,  2048, 512, 1048576LL, 1048576LL, 0LL, 1);
  k_tcvt<<<dim3(1000, 16, 1), tcb, 0, stream>>>(Wlm, wlmb, 512, 32000, 0LL, 0LL, 0LL, 1);

  k_embed<<<dim3(MROWS), dim3(128), 0, stream>>>(idx, midx, tok, metae, x);

  for (int l = 0; l < LL; ++l) {
    k_rowstat<<<dim3(515), dim3(64, 4), 0, stream>>>(x, mu_, rs_);
    k_gemm<0, false, false, 1, 128, false><<<dim3(17, 12), 256, 0, stream>>>(
        nullptr, x, mu_, rs_, ln1g + l * 512, ln1b + l * 512,
        wqkvb + (size_t)l * 786432, nullptr, nullptr, nullptr, qkv, MROWS, 1536, 512);
    k_attn<<<dim3(17, 8, 2), 256, 0, stream>>>(qkv, obuf);
    k_gemm<1, false, true, 0, 64, false><<<dim3(17, 8), 256, 0, stream>>>(
        obuf, nullptr, nullptr, nullptr, nullptr, nullptr,
        wob + (size_t)l * 262144, bo + l * 512, x, x, nullptr, MROWS, 512, 512);
    k_rowstat<<<dim3(515), dim3(64, 4), 0, stream>>>(x, mu_, rs_);
    k_gemm<0, true, true, 1, 128, false><<<dim3(17, 16), 256, 0, stream>>>(
        nullptr, x, mu_, rs_, ln2g + l * 512, ln2b + l * 512,
        w1b + (size_t)l * 1048576, b1 + l * 2048, nullptr, nullptr, f1, MROWS, 2048, 512);
    k_gemm<1, false, true, 0, 64, false><<<dim3(17, 8), 256, 0, stream>>>(
        f1, nullptr, nullptr, nullptr, nullptr, nullptr,
        w2b + (size_t)l * 1048576, b2 + l * 512, x, x, nullptr, MROWS, 512, 2048);
  }

  k_rowstat<<<dim3(515), dim3(64, 4), 0, stream>>>(x, mu_, rs_);
  k_gemm<2, false, true, 1, 128, true><<<dim3(16, 250), 256, 0, stream>>>(
      nullptr, x, mu_, rs_, lnfg, lnfb,
      wlmb, blm, nullptr, out, nullptr, 2048, NVOCAB, 512);
}

// Round 3
// 1143.141 us; speedup vs baseline: 1.2143x; 1.1715x over previous
//
#include <hip/hip_runtime.h>
#include <hip/hip_bf16.h>
#include <math.h>

// ---------------- problem constants ----------------
#define TT     1024      // T
#define METAN  6
#define TT1    1030      // T + META
#define BB     2
#define DD     512
#define HH     8
#define HSZ    64
#define LL     6
#define NVOCAB 32000
#define MROWS  2060      // B*T1
#define MPAD   2176      // 17 * 128
#define SCALE  0.044194173824159216f   // 512^-0.5

typedef float  f32x4  __attribute__((ext_vector_type(4)));
typedef __bf16 bf16x8 __attribute__((ext_vector_type(8)));

__device__ __forceinline__ __bf16 f2bf(float f) {
  unsigned int u = __builtin_bit_cast(unsigned int, f);
  u = u + 0x7FFFu + ((u >> 16) & 1u);           // RNE
  unsigned short h = (unsigned short)(u >> 16);
  return __builtin_bit_cast(__bf16, h);
}

// normalize 8 fp32 (pointer form) -> bf16x8
__device__ __forceinline__ bf16x8 ln8(const float* __restrict__ xp, float mu, float rs,
                                      const float* __restrict__ g, const float* __restrict__ b) {
  float4 v0 = *(const float4*)xp,     v1 = *(const float4*)(xp + 4);
  float4 g0 = *(const float4*)g,      g1 = *(const float4*)(g + 4);
  float4 b0 = *(const float4*)b,      b1 = *(const float4*)(b + 4);
  float vv[8] = {v0.x, v0.y, v0.z, v0.w, v1.x, v1.y, v1.z, v1.w};
  float gg[8] = {g0.x, g0.y, g0.z, g0.w, g1.x, g1.y, g1.z, g1.w};
  float bb[8] = {b0.x, b0.y, b0.z, b0.w, b1.x, b1.y, b1.z, b1.w};
  bf16x8 r;
#pragma unroll
  for (int j = 0; j < 8; j++) r[j] = f2bf((vv[j] - mu) * rs * gg[j] + bb[j]);
  return r;
}

// register-value form
__device__ __forceinline__ bf16x8 ln8v(float4 v0, float4 v1, float mu, float rs,
                                       float4 g0, float4 g1, float4 b0, float4 b1) {
  float vv[8] = {v0.x, v0.y, v0.z, v0.w, v1.x, v1.y, v1.z, v1.w};
  float gg[8] = {g0.x, g0.y, g0.z, g0.w, g1.x, g1.y, g1.z, g1.w};
  float bb[8] = {b0.x, b0.y, b0.z, b0.w, b1.x, b1.y, b1.z, b1.w};
  bf16x8 r;
#pragma unroll
  for (int j = 0; j < 8; j++) r[j] = f2bf((vv[j] - mu) * rs * gg[j] + bb[j]);
  return r;
}

// ---------------- embedding + positional encoding + LN partials ----------------
__global__ void k_embed(const int* __restrict__ idx, const int* __restrict__ midx,
                        const float* __restrict__ tok, const float* __restrict__ met,
                        float* __restrict__ x, float* __restrict__ ps, float* __restrict__ pq)
{
  int row = blockIdx.x;
  int b = row / TT1, t = row - b * TT1;
  int d0 = threadIdx.x * 4;
  float v[4];
  if (t < TT) {
    const float* e = tok + (size_t)idx[b * TT + t] * DD;
    float pos = (float)(t / 6);
#pragma unroll
    for (int j = 0; j < 4; j += 2) {
      int i = (d0 + j) >> 1;
      float dv = expf((float)i * (-2.0f * 9.210340371976184f / 512.0f));
      float ang = pos * dv;
      v[j]     = e[d0 + j]     + sinf(ang);
      v[j + 1] = e[d0 + j + 1] + cosf(ang);
    }
  } else {
    const float* e = met + (size_t)midx[b * METAN + (t - TT)] * DD;
#pragma unroll
    for (int j = 0; j < 4; j++) v[j] = e[d0 + j];
  }
  *(float4*)&x[(size_t)row * DD + d0] = *(float4*)v;
  float s = v[0] + v[1] + v[2] + v[3];
  float q = v[0]*v[0] + v[1]*v[1] + v[2]*v[2] + v[3]*v[3];
#pragma unroll
  for (int msk = 1; msk < 16; msk <<= 1) { s += __shfl_xor(s, msk); q += __shfl_xor(q, msk); }
  if ((threadIdx.x & 15) == 0) {
    ps[(size_t)row * 8 + (threadIdx.x >> 4)] = s;
    pq[(size_t)row * 8 + (threadIdx.x >> 4)] = q;
  }
}

// ---------------- final LN -> compact bf16 rows for LM head ----------------
// grid 512 x (64,4): compact row r -> source row (r>>10)*1030 + (r&1023)
__global__ void k_lnp(const float* __restrict__ x, const float* __restrict__ ps,
                      const float* __restrict__ pq, const float* __restrict__ g,
                      const float* __restrict__ b, __bf16* __restrict__ xf)
{
  int row = blockIdx.x * 4 + threadIdx.y;
  int sr = (row >> 10) * TT1 + (row & 1023);
  int lane = threadIdx.x;
  float s = 0.f, q = 0.f;
#pragma unroll
  for (int j = 0; j < 8; j++) { s += ps[(size_t)sr * 8 + j]; q += pq[(size_t)sr * 8 + j]; }
  float mu = s * (1.0f / 512.0f);
  float rs = rsqrtf(fmaxf(q * (1.0f / 512.0f) - mu * mu, 0.f) + 1e-5f);
  bf16x8 o = ln8(&x[(size_t)sr * DD + lane * 8], mu, rs, &g[lane * 8], &b[lane * 8]);
  *(bf16x8*)&xf[(size_t)row * DD + lane * 8] = o;
}

// ---------------- transpose + fp32->bf16 weight conversion ----------------
__global__ void k_tcvt(const float* __restrict__ in, __bf16* __restrict__ out,
                       int R, int C, long long in_bs,
                       long long bs_hi, long long bs_lo, int lo_cnt)
{
  __shared__ float t[32][33];
  int bb = blockIdx.z;
  const float* ib = in + (long long)bb * in_bs;
  __bf16* ob = out + (long long)(bb / lo_cnt) * bs_hi + (long long)(bb % lo_cnt) * bs_lo;
  int c = blockIdx.x * 32 + threadIdx.x;
  for (int j = threadIdx.y; j < 32; j += 8)
    t[j][threadIdx.x] = ib[(size_t)(blockIdx.y * 32 + j) * C + c];
  __syncthreads();
  int r = blockIdx.y * 32 + threadIdx.x;
  for (int j = threadIdx.y; j < 32; j += 8)
    ob[(size_t)(blockIdx.x * 32 + j) * R + r] = f2bf(t[threadIdx.x][j]);
}

// ---------------- generic bf16 GEMM with register prefetch ----------------
// M-tile 128, N-tile NT (128: 2x2 waves; 64: 4x1 waves), BK=32, XOR-swizzled LDS.
// AMODE 0: A bf16 [.][K].  AMODE 1: A = layernorm(Ax fp32 row) on the fly, mu/rs from partials.
// MODE 0: outb = bf16(acc (+bias) (ReLU));  MODE 1: outf = res + acc + bias (+STAT partials);
// MODE 2: outf = acc + bias.
template <int MODE, bool RELU, bool BIAS, int AMODE, int NT, bool STAT>
__global__ __launch_bounds__(256) void k_gemm(
    const __bf16* __restrict__ A, const float* __restrict__ Ax,
    const float* __restrict__ ps, const float* __restrict__ pq,
    const float* __restrict__ lng, const float* __restrict__ lnb,
    const __bf16* __restrict__ Bt, const float* __restrict__ bias,
    const float* __restrict__ res,
    float* __restrict__ outf, __bf16* __restrict__ outb,
    float* __restrict__ ops, float* __restrict__ opq,
    int M, int N, int K)
{
  __shared__ __align__(16) __bf16 As[4096];        // 128 x 32
  __shared__ __align__(16) __bf16 Bs[NT * 32];
  const int tid = threadIdx.x;
  const int lane = tid & 63, w = tid >> 6;
  const int wm = (NT == 128) ? (w >> 1) : w;
  const int wn = (NT == 128) ? (w & 1) : 0;
  const int MR = (NT == 128) ? 4 : 2;
  const int WMS = (NT == 128) ? 64 : 32;
  const int rm = lane & 15, g4 = lane >> 4;

  // XCD-bijective swizzle (row-tile fastest inside each XCD chunk)
  const int nbx = gridDim.x;
  int flat = blockIdx.y * nbx + blockIdx.x;
  {
    const int nwg = nbx * gridDim.y;
    const int q = nwg >> 3, rr = nwg & 7;
    const int xcd = flat & 7, ii = flat >> 3;
    flat = (xcd < rr ? xcd * (q + 1) : rr * (q + 1) + (xcd - rr) * q) + ii;
  }
  const int row0 = (flat % nbx) * 128;
  const int col0 = (flat / nbx) * NT;

  f32x4 acc[MR][4];
  const f32x4 fz = {0.f, 0.f, 0.f, 0.f};
#pragma unroll
  for (int i = 0; i < MR; i++)
#pragma unroll
    for (int j = 0; j < 4; j++) acc[i][j] = fz;

  const int srow = tid >> 2, skc = tid & 3;
  const int wA0 = (((srow * 4 + skc) ^ (srow & 7)) * 8);
  const int wA1 = ((((srow + 64) * 4 + skc) ^ (srow & 7)) * 8);

  // A staging pointers + LN stats
  const __bf16* Ag = nullptr;
  const float *Ax0 = nullptr, *Ax1 = nullptr, *gk = nullptr, *bk = nullptr;
  float mu0 = 0.f, rs0 = 0.f, mu1 = 0.f, rs1 = 0.f;
  if (AMODE == 0) {
    Ag = A + (size_t)(row0 + srow) * K + skc * 8;
  } else {
    int sa0 = row0 + srow, sa1 = sa0 + 64;
    Ax0 = Ax + (size_t)sa0 * DD + skc * 8;
    Ax1 = Ax + (size_t)sa1 * DD + skc * 8;
    float s0 = 0.f, q0 = 0.f, s1 = 0.f, q1 = 0.f;
#pragma unroll
    for (int j = 0; j < 8; j++) {
      s0 += ps[(size_t)sa0 * 8 + j]; q0 += pq[(size_t)sa0 * 8 + j];
      s1 += ps[(size_t)sa1 * 8 + j]; q1 += pq[(size_t)sa1 * 8 + j];
    }
    mu0 = s0 * (1.0f / 512.0f);
    rs0 = rsqrtf(fmaxf(q0 * (1.0f / 512.0f) - mu0 * mu0, 0.f) + 1e-5f);
    mu1 = s1 * (1.0f / 512.0f);
    rs1 = rsqrtf(fmaxf(q1 * (1.0f / 512.0f) - mu1 * mu1, 0.f) + 1e-5f);
    gk = lng + skc * 8; bk = lnb + skc * 8;
  }
  const __bf16* Bg = Bt + (size_t)(col0 + srow) * K + skc * 8;

  // prefetch registers
  bf16x8 pa0, pa1, pbb0, pbb1;
  float4 f00, f01, f10, f11, pg0, pg1, pc0, pc1;

  auto prefetch = [&](int kk) {
    if (AMODE == 0) {
      pa0 = *(const bf16x8*)(Ag + kk);
      pa1 = *(const bf16x8*)(Ag + (size_t)64 * K + kk);
    } else {
      f00 = *(const float4*)(Ax0 + kk); f01 = *(const float4*)(Ax0 + kk + 4);
      f10 = *(const float4*)(Ax1 + kk); f11 = *(const float4*)(Ax1 + kk + 4);
      pg0 = *(const float4*)(gk + kk);  pg1 = *(const float4*)(gk + kk + 4);
      pc0 = *(const float4*)(bk + kk);  pc1 = *(const float4*)(bk + kk + 4);
    }
    pbb0 = *(const bf16x8*)(Bg + kk);
    if (NT == 128) pbb1 = *(const bf16x8*)(Bg + (size_t)64 * K + kk);
  };

  prefetch(0);

  for (int k0 = 0; k0 < K; k0 += 32) {
    bf16x8 a0, a1;
    if (AMODE == 0) { a0 = pa0; a1 = pa1; }
    else {
      a0 = ln8v(f00, f01, mu0, rs0, pg0, pg1, pc0, pc1);
      a1 = ln8v(f10, f11, mu1, rs1, pg0, pg1, pc0, pc1);
    }
    bf16x8 b0 = pbb0, b1 = pbb1;
    __syncthreads();                 // previous iter's frag reads done
    *(bf16x8*)&As[wA0] = a0;
    *(bf16x8*)&As[wA1] = a1;
    *(bf16x8*)&Bs[wA0] = b0;
    if (NT == 128) *(bf16x8*)&Bs[wA1] = b1;
    if (k0 + 32 < K) prefetch(k0 + 32);   // loads fly during MFMA below
    __syncthreads();
    bf16x8 af[MR], bfr[4];
#pragma unroll
    for (int m = 0; m < MR; m++) {
      int r = wm * WMS + m * 16 + rm;
      af[m] = *(const bf16x8*)&As[((r * 4 + g4) ^ (r & 7)) * 8];
    }
#pragma unroll
    for (int n = 0; n < 4; n++) {
      int r = wn * 64 + n * 16 + rm;
      bfr[n] = *(const bf16x8*)&Bs[((r * 4 + g4) ^ (r & 7)) * 8];
    }
#pragma unroll
    for (int m = 0; m < MR; m++)
#pragma unroll
      for (int n = 0; n < 4; n++)
        acc[m][n] = __builtin_amdgcn_mfma_f32_16x16x32_bf16(af[m], bfr[n], acc[m][n], 0, 0, 0);
  }

#pragma unroll
  for (int m = 0; m < MR; m++) {
    int row_b = row0 + wm * WMS + m * 16 + g4 * 4;
    float bv[4];
#pragma unroll
    for (int n = 0; n < 4; n++) bv[n] = BIAS ? bias[col0 + wn * 64 + n * 16 + rm] : 0.f;
#pragma unroll
    for (int r = 0; r < 4; r++) {
      int row = row_b + r;
      float s = 0.f, qq = 0.f;
#pragma unroll
      for (int n = 0; n < 4; n++) {
        int col = col0 + wn * 64 + n * 16 + rm;
        float v = acc[m][n][r] + bv[n];
        if (MODE == 0) {
          if (RELU) v = fmaxf(v, 0.f);
          if (row < M) outb[(size_t)row * N + col] = f2bf(v);
        } else if (MODE == 1) {
          if (row < M) { v += res[(size_t)row * N + col]; outf[(size_t)row * N + col] = v; }
          s += v; qq += v * v;
        } else {
          if (row < M) outf[(size_t)row * N + col] = v;
        }
      }
      if (MODE == 1 && STAT) {
#pragma unroll
        for (int msk = 1; msk < 16; msk <<= 1) { s += __shfl_xor(s, msk); qq += __shfl_xor(qq, msk); }
        if (rm == 0 && row < M) {
          ops[(size_t)row * 8 + (col0 >> 6)] = s;
          opq[(size_t)row * 8 + (col0 >> 6)] = qq;
        }
      }
    }
  }
}

// ---------------- fused masked attention (flash-style) ----------------
__global__ __launch_bounds__(256) void k_attn(const __bf16* __restrict__ qkv,
                                              __bf16* __restrict__ ob)
{
  __shared__ __align__(16) __bf16 Ks[32][72];
  __shared__ __align__(16) __bf16 Vs[64][40];
  __shared__ __align__(16) __bf16 Ps[4][16][40];

  const int tid = threadIdx.x;
  const int lane = tid & 63, w = tid >> 6;
  const int rm = lane & 15, g4 = lane >> 4;
  const int q0 = blockIdx.x * 64;
  const int h = blockIdx.y, b = blockIdx.z;
  const int qw = q0 + w * 16;

  const size_t rsd = 1536;
  const __bf16* qb = qkv + (size_t)b * TT1 * rsd + h * HSZ;
  const __bf16* kb = qb + 512;
  const __bf16* vb = qb + 1024;

  bf16x8 aq[2];
  {
    const __bf16* qp = qb + (size_t)(qw + rm) * rsd + 8 * g4;
    aq[0] = *(const bf16x8*)qp;
    aq[1] = *(const bf16x8*)(qp + 32);
  }

  int ae_[4];
#pragma unroll
  for (int r = 0; r < 4; r++) {
    int qr = qw + g4 * 4 + r;
    ae_[r] = (qr / 6 + 1) * 6;
  }

  float m_[4], l_[4];
  f32x4 accO[4];
  const f32x4 fz = {0.f, 0.f, 0.f, 0.f};
#pragma unroll
  for (int j = 0; j < 4; j++) accO[j] = fz;
#pragma unroll
  for (int r = 0; r < 4; r++) { m_[r] = -1e30f; l_[r] = 0.f; }

  int aemax = ((q0 + 63) / 6 + 1) * 6;
  if (aemax > TT) aemax = TT;
  const int ntile = (aemax + 31) >> 5;

  const int skey = tid >> 3;
  const int shs = (tid & 7) * 8;

  for (int tt = 0; tt <= ntile; ++tt) {
    const bool meta = (tt == ntile);
    const int kt = meta ? TT : tt * 32;

    bf16x8 kv_k = *(const bf16x8*)(kb + (size_t)(kt + skey) * rsd + shs);
    bf16x8 kv_v = *(const bf16x8*)(vb + (size_t)(kt + skey) * rsd + shs);
    __syncthreads();
    *(bf16x8*)&Ks[skey][shs] = kv_k;
#pragma unroll
    for (int j = 0; j < 8; j++) Vs[shs + j][skey] = kv_v[j];
    __syncthreads();

    f32x4 s[2];
#pragma unroll
    for (int nt = 0; nt < 2; nt++) {
      f32x4 a = fz;
      bf16x8 bk0 = *(const bf16x8*)&Ks[nt * 16 + rm][8 * g4];
      bf16x8 bk1 = *(const bf16x8*)&Ks[nt * 16 + rm][32 + 8 * g4];
      a = __builtin_amdgcn_mfma_f32_16x16x32_bf16(aq[0], bk0, a, 0, 0, 0);
      a = __builtin_amdgcn_mfma_f32_16x16x32_bf16(aq[1], bk1, a, 0, 0, 0);
      s[nt] = a;
    }

    float alpha[4];
#pragma unroll
    for (int r = 0; r < 4; r++) {
      float s0 = s[0][r] * SCALE;
      float s1 = s[1][r] * SCALE;
      int col0k = kt + rm;
      int lim = meta ? TT1 : ae_[r];
      if (col0k >= lim) s0 = -1e30f;
      if (col0k + 16 >= lim) s1 = -1e30f;
      float tm = fmaxf(s0, s1);
#pragma unroll
      for (int msk = 1; msk < 16; msk <<= 1) tm = fmaxf(tm, __shfl_xor(tm, msk));
      float mn = fmaxf(m_[r], tm);
      float p0 = __expf(s0 - mn);
      float p1 = __expf(s1 - mn);
      float ts = p0 + p1;
#pragma unroll
      for (int msk = 1; msk < 16; msk <<= 1) ts += __shfl_xor(ts, msk);
      alpha[r] = __expf(m_[r] - mn);
      l_[r] = l_[r] * alpha[r] + ts;
      m_[r] = mn;
      Ps[w][g4 * 4 + r][rm]      = f2bf(p0);
      Ps[w][g4 * 4 + r][rm + 16] = f2bf(p1);
    }
#pragma unroll
    for (int j = 0; j < 4; j++)
#pragma unroll
      for (int r = 0; r < 4; r++) accO[j][r] *= alpha[r];
    __syncthreads();

    bf16x8 pa = *(const bf16x8*)&Ps[w][rm][8 * g4];
#pragma unroll
    for (int j = 0; j < 4; j++) {
      bf16x8 bv = *(const bf16x8*)&Vs[j * 16 + rm][8 * g4];
      accO[j] = __builtin_amdgcn_mfma_f32_16x16x32_bf16(pa, bv, accO[j], 0, 0, 0);
    }
  }

#pragma unroll
  for (int r = 0; r < 4; r++) {
    int q = qw + g4 * 4 + r;
    if (q < TT1) {
      float rl = 1.0f / l_[r];
#pragma unroll
      for (int j = 0; j < 4; j++)
        ob[((size_t)b * TT1 + q) * DD + h * HSZ + j * 16 + rm] = f2bf(accO[j][r] * rl);
    }
  }
}

// ---------------- host launcher ----------------
extern "C" void kernel_launch(void* const* d_in, const int* in_sizes, int n_in,
                              void* d_out, int out_size, void* d_ws, size_t ws_size,
                              hipStream_t stream)
{
  const int*   idx   = (const int*)d_in[0];
  const int*   midx  = (const int*)d_in[1];
  const float* tok   = (const float*)d_in[2];
  const float* metae = (const float*)d_in[3];
  const float* Wq    = (const float*)d_in[4];
  const float* Wk    = (const float*)d_in[5];
  const float* Wv    = (const float*)d_in[6];
  const float* Wo    = (const float*)d_in[7];
  const float* bo    = (const float*)d_in[8];
  const float* W1    = (const float*)d_in[9];
  const float* b1    = (const float*)d_in[10];
  const float* W2    = (const float*)d_in[11];
  const float* b2    = (const float*)d_in[12];
  const float* ln1g  = (const float*)d_in[13];
  const float* ln1b  = (const float*)d_in[14];
  const float* ln2g  = (const float*)d_in[15];
  const float* ln2b  = (const float*)d_in[16];
  const float* lnfg  = (const float*)d_in[17];
  const float* lnfb  = (const float*)d_in[18];
  const float* Wlm   = (const float*)d_in[19];
  const float* blm   = (const float*)d_in[20];
  float* out = (float*)d_out;

  char* p = (char*)d_ws;
  auto alloc = [&](size_t bytes) { void* r = (void*)p; p += (bytes + 255) & ~(size_t)255; return r; };
  float*  x     = (float*)alloc((size_t)MPAD * 512 * 4);
  float*  ps_   = (float*)alloc((size_t)MPAD * 8 * 4);
  float*  pq_   = (float*)alloc((size_t)MPAD * 8 * 4);
  __bf16* qkv   = (__bf16*)alloc((size_t)MPAD * 1536 * 2);
  __bf16* obuf  = (__bf16*)alloc((size_t)MPAD * 512 * 2);
  __bf16* f1    = (__bf16*)alloc((size_t)MPAD * 2048 * 2);
  __bf16* xf    = (__bf16*)alloc((size_t)2048 * 512 * 2);
  __bf16* wqkvb = (__bf16*)alloc((size_t)6 * 1536 * 512 * 2);
  __bf16* wob   = (__bf16*)alloc((size_t)6 * 512 * 512 * 2);
  __bf16* w1b   = (__bf16*)alloc((size_t)6 * 2048 * 512 * 2);
  __bf16* w2b   = (__bf16*)alloc((size_t)6 * 512 * 2048 * 2);
  __bf16* wlmb  = (__bf16*)alloc((size_t)NVOCAB * 512 * 2);
  (void)in_sizes; (void)n_in; (void)out_size; (void)ws_size;

  dim3 tcb(32, 8);
  k_tcvt<<<dim3(2, 16, 48), tcb, 0, stream>>>(Wq, wqkvb,          512, 64,   32768LL,  786432LL, 32768LL, 8);
  k_tcvt<<<dim3(2, 16, 48), tcb, 0, stream>>>(Wk, wqkvb + 262144, 512, 64,   32768LL,  786432LL, 32768LL, 8);
  k_tcvt<<<dim3(2, 16, 48), tcb, 0, stream>>>(Wv, wqkvb + 524288, 512, 64,   32768LL,  786432LL, 32768LL, 8);
  k_tcvt<<<dim3(16, 16, 6), tcb, 0, stream>>>(Wo, wob,  512, 512,  262144LL,  262144LL, 0LL, 1);
  k_tcvt<<<dim3(64, 16, 6), tcb, 0, stream>>>(W1, w1b,  512, 2048, 1048576LL, 1048576LL, 0LL, 1);
  k_tcvt<<<dim3(16, 64, 6), tcb, 0, stream>>>(W2, w2b,  2048, 512, 1048576LL, 1048576LL, 0LL, 1);
  k_tcvt<<<dim3(1000, 16, 1), tcb, 0, stream>>>(Wlm, wlmb, 512, 32000, 0LL, 0LL, 0LL, 1);

  k_embed<<<dim3(MROWS), dim3(128), 0, stream>>>(idx, midx, tok, metae, x, ps_, pq_);

  for (int l = 0; l < LL; ++l) {
    // QKV projection with fused ln1
    k_gemm<0, false, false, 1, 128, false><<<dim3(17, 12), 256, 0, stream>>>(
        nullptr, x, ps_, pq_, ln1g + l * 512, ln1b + l * 512,
        wqkvb + (size_t)l * 786432, nullptr, nullptr, nullptr, qkv,
        nullptr, nullptr, MROWS, 1536, 512);
    k_attn<<<dim3(17, 8, 2), 256, 0, stream>>>(qkv, obuf);
    // Wo projection + residual + LN partials (for ln2)
    k_gemm<1, false, true, 0, 64, true><<<dim3(17, 8), 256, 0, stream>>>(
        obuf, nullptr, nullptr, nullptr, nullptr, nullptr,
        wob + (size_t)l * 262144, bo + l * 512, x, x, nullptr,
        ps_, pq_, MROWS, 512, 512);
    // FFN1 with fused ln2
    k_gemm<0, true, true, 1, 128, false><<<dim3(17, 16), 256, 0, stream>>>(
        nullptr, x, ps_, pq_, ln2g + l * 512, ln2b + l * 512,
        w1b + (size_t)l * 1048576, b1 + l * 2048, nullptr, nullptr, f1,
        nullptr, nullptr, MROWS, 2048, 512);
    // FFN2 + residual + LN partials (for next ln1 / final ln)
    k_gemm<1, false, true, 0, 64, true><<<dim3(17, 8), 256, 0, stream>>>(
        f1, nullptr, nullptr, nullptr, nullptr, nullptr,
        w2b + (size_t)l * 1048576, b2 + l * 512, x, x, nullptr,
        ps_, pq_, MROWS, 512, 2048);
  }

  // final LN -> compact bf16 rows, then LM head
  k_lnp<<<dim3(512), dim3(64, 4), 0, stream>>>(x, ps_, pq_, lnfg, lnfb, xf);
  k_gemm<2, false, true, 0, 128, false><<<dim3(16, 250), 256, 0, stream>>>(
      xf, nullptr, nullptr, nullptr, nullptr, nullptr,
      wlmb, blm, nullptr, out, nullptr, nullptr, nullptr, 2048, NVOCAB, 512);
}

// Round 4
// 1128.492 us; speedup vs baseline: 1.2301x; 1.0130x over previous
//
#include <hip/hip_runtime.h>
#include <hip/hip_bf16.h>
#include <math.h>

// ---------------- problem constants ----------------
#define TT     1024      // T
#define METAN  6
#define TT1    1030      // T + META
#define BB     2
#define DD     512
#define HH     8
#define HSZ    64
#define LL     6
#define NVOCAB 32000
#define MROWS  2060      // B*T1
#define MPAD   2176      // 17 * 128
#define SCALE  0.044194173824159216f   // 512^-0.5

typedef float  f32x4  __attribute__((ext_vector_type(4)));
typedef __bf16 bf16x8 __attribute__((ext_vector_type(8)));

__device__ __forceinline__ __bf16 f2bf(float f) {
  unsigned int u = __builtin_bit_cast(unsigned int, f);
  u = u + 0x7FFFu + ((u >> 16) & 1u);           // RNE
  unsigned short h = (unsigned short)(u >> 16);
  return __builtin_bit_cast(__bf16, h);
}

// normalize 8 fp32 (pointer form) -> bf16x8
__device__ __forceinline__ bf16x8 ln8(const float* __restrict__ xp, float mu, float rs,
                                      const float* __restrict__ g, const float* __restrict__ b) {
  float4 v0 = *(const float4*)xp,     v1 = *(const float4*)(xp + 4);
  float4 g0 = *(const float4*)g,      g1 = *(const float4*)(g + 4);
  float4 b0 = *(const float4*)b,      b1 = *(const float4*)(b + 4);
  float vv[8] = {v0.x, v0.y, v0.z, v0.w, v1.x, v1.y, v1.z, v1.w};
  float gg[8] = {g0.x, g0.y, g0.z, g0.w, g1.x, g1.y, g1.z, g1.w};
  float bb[8] = {b0.x, b0.y, b0.z, b0.w, b1.x, b1.y, b1.z, b1.w};
  bf16x8 r;
#pragma unroll
  for (int j = 0; j < 8; j++) r[j] = f2bf((vv[j] - mu) * rs * gg[j] + bb[j]);
  return r;
}

// register-value form
__device__ __forceinline__ bf16x8 ln8v(float4 v0, float4 v1, float mu, float rs,
                                       float4 g0, float4 g1, float4 b0, float4 b1) {
  float vv[8] = {v0.x, v0.y, v0.z, v0.w, v1.x, v1.y, v1.z, v1.w};
  float gg[8] = {g0.x, g0.y, g0.z, g0.w, g1.x, g1.y, g1.z, g1.w};
  float bb[8] = {b0.x, b0.y, b0.z, b0.w, b1.x, b1.y, b1.z, b1.w};
  bf16x8 r;
#pragma unroll
  for (int j = 0; j < 8; j++) r[j] = f2bf((vv[j] - mu) * rs * gg[j] + bb[j]);
  return r;
}

// ---------------- embedding + positional encoding + LN partials ----------------
__global__ void k_embed(const int* __restrict__ idx, const int* __restrict__ midx,
                        const float* __restrict__ tok, const float* __restrict__ met,
                        float* __restrict__ x, float* __restrict__ ps, float* __restrict__ pq)
{
  int row = blockIdx.x;
  int b = row / TT1, t = row - b * TT1;
  int d0 = threadIdx.x * 4;
  float v[4];
  if (t < TT) {
    const float* e = tok + (size_t)idx[b * TT + t] * DD;
    float pos = (float)(t / 6);
#pragma unroll
    for (int j = 0; j < 4; j += 2) {
      int i = (d0 + j) >> 1;
      float dv = expf((float)i * (-2.0f * 9.210340371976184f / 512.0f));
      float ang = pos * dv;
      v[j]     = e[d0 + j]     + sinf(ang);
      v[j + 1] = e[d0 + j + 1] + cosf(ang);
    }
  } else {
    const float* e = met + (size_t)midx[b * METAN + (t - TT)] * DD;
#pragma unroll
    for (int j = 0; j < 4; j++) v[j] = e[d0 + j];
  }
  *(float4*)&x[(size_t)row * DD + d0] = *(float4*)v;
  float s = v[0] + v[1] + v[2] + v[3];
  float q = v[0]*v[0] + v[1]*v[1] + v[2]*v[2] + v[3]*v[3];
#pragma unroll
  for (int msk = 1; msk < 16; msk <<= 1) { s += __shfl_xor(s, msk); q += __shfl_xor(q, msk); }
  if ((threadIdx.x & 15) == 0) {
    ps[(size_t)row * 8 + (threadIdx.x >> 4)] = s;
    pq[(size_t)row * 8 + (threadIdx.x >> 4)] = q;
  }
}

// ---------------- final LN -> compact bf16 rows for LM head ----------------
__global__ void k_lnp(const float* __restrict__ x, const float* __restrict__ ps,
                      const float* __restrict__ pq, const float* __restrict__ g,
                      const float* __restrict__ b, __bf16* __restrict__ xf)
{
  int row = blockIdx.x * 4 + threadIdx.y;
  int sr = (row >> 10) * TT1 + (row & 1023);
  int lane = threadIdx.x;
  float s = 0.f, q = 0.f;
#pragma unroll
  for (int j = 0; j < 8; j++) { s += ps[(size_t)sr * 8 + j]; q += pq[(size_t)sr * 8 + j]; }
  float mu = s * (1.0f / 512.0f);
  float rs = rsqrtf(fmaxf(q * (1.0f / 512.0f) - mu * mu, 0.f) + 1e-5f);
  bf16x8 o = ln8(&x[(size_t)sr * DD + lane * 8], mu, rs, &g[lane * 8], &b[lane * 8]);
  *(bf16x8*)&xf[(size_t)row * DD + lane * 8] = o;
}

// ---------------- transpose + fp32->bf16 weight conversion ----------------
__global__ void k_tcvt(const float* __restrict__ in, __bf16* __restrict__ out,
                       int R, int C, long long in_bs,
                       long long bs_hi, long long bs_lo, int lo_cnt)
{
  __shared__ float t[32][33];
  int bb = blockIdx.z;
  const float* ib = in + (long long)bb * in_bs;
  __bf16* ob = out + (long long)(bb / lo_cnt) * bs_hi + (long long)(bb % lo_cnt) * bs_lo;
  int c = blockIdx.x * 32 + threadIdx.x;
  for (int j = threadIdx.y; j < 32; j += 8)
    t[j][threadIdx.x] = ib[(size_t)(blockIdx.y * 32 + j) * C + c];
  __syncthreads();
  int r = blockIdx.y * 32 + threadIdx.x;
  for (int j = threadIdx.y; j < 32; j += 8)
    ob[(size_t)(blockIdx.x * 32 + j) * R + r] = f2bf(t[threadIdx.x][j]);
}

// ---------------- generic bf16 GEMM, double-buffered LDS, reg prefetch ----------------
// Tile MT x NT, BK=32, 4 waves as WM x (4/WM), XOR-swizzled LDS, ONE barrier/K-step.
// AMODE 0: A bf16 [.][K].  AMODE 1: A = layernorm(Ax fp32 row) on the fly (MT=64 only).
// MODE 0: outb = bf16(acc (+bias) (ReLU));  MODE 1: outf = res + acc + bias (+STAT: requires WM=4);
// MODE 2: outf = acc + bias.
template <int MODE, bool RELU, bool BIAS, int AMODE, int MT, int NT, int WM, bool STAT>
__global__ __launch_bounds__(256) void k_gemm(
    const __bf16* __restrict__ A, const float* __restrict__ Ax,
    const float* __restrict__ ps, const float* __restrict__ pq,
    const float* __restrict__ lng, const float* __restrict__ lnb,
    const __bf16* __restrict__ Bt, const float* __restrict__ bias,
    const float* __restrict__ res,
    float* __restrict__ outf, __bf16* __restrict__ outb,
    float* __restrict__ ops, float* __restrict__ opq,
    int M, int N, int K)
{
  constexpr int WN  = 4 / WM;
  constexpr int WMS = MT / WM;         // rows per wave
  constexpr int WNS = NT / WN;         // cols per wave
  constexpr int MR  = WMS / 16;
  constexpr int NR  = WNS / 16;
  constexpr int AR2 = (MT == 128) ? 1 : 0;   // second A staging round?
  constexpr int BR2 = (NT == 128) ? 1 : 0;

  __shared__ __align__(16) __bf16 As[2][MT * 32];
  __shared__ __align__(16) __bf16 Bs[2][NT * 32];
  const int tid = threadIdx.x;
  const int lane = tid & 63, w = tid >> 6;
  const int wm = (WN == 1) ? w : (w >> 1);
  const int wn = (WN == 1) ? 0 : (w & 1);
  const int rm = lane & 15, g4 = lane >> 4;

  // XCD-bijective swizzle (row-tile fastest inside each XCD chunk)
  const int nbx = gridDim.x;
  int flat = blockIdx.y * nbx + blockIdx.x;
  {
    const int nwg = nbx * gridDim.y;
    const int q = nwg >> 3, rr = nwg & 7;
    const int xcd = flat & 7, ii = flat >> 3;
    flat = (xcd < rr ? xcd * (q + 1) : rr * (q + 1) + (xcd - rr) * q) + ii;
  }
  const int row0 = (flat % nbx) * MT;
  const int col0 = (flat / nbx) * NT;

  f32x4 acc[MR][NR];
  const f32x4 fz = {0.f, 0.f, 0.f, 0.f};
#pragma unroll
  for (int i = 0; i < MR; i++)
#pragma unroll
    for (int j = 0; j < NR; j++) acc[i][j] = fz;

  const int srow = tid >> 2, skc = tid & 3;
  const int wA0 = (((srow * 4 + skc) ^ (srow & 7)) * 8);
  const int wA1 = ((((srow + 64) * 4 + skc) ^ (srow & 7)) * 8);

  // A staging pointers + LN stats
  const __bf16* Ag = nullptr;
  const float *Ax0 = nullptr, *gk = nullptr, *bk = nullptr;
  float mu0 = 0.f, rs0 = 0.f;
  if (AMODE == 0) {
    Ag = A + (size_t)(row0 + srow) * K + skc * 8;
  } else {
    int sa0 = row0 + srow;
    Ax0 = Ax + (size_t)sa0 * DD + skc * 8;
    float s0 = 0.f, q0 = 0.f;
#pragma unroll
    for (int j = 0; j < 8; j++) { s0 += ps[(size_t)sa0 * 8 + j]; q0 += pq[(size_t)sa0 * 8 + j]; }
    mu0 = s0 * (1.0f / 512.0f);
    rs0 = rsqrtf(fmaxf(q0 * (1.0f / 512.0f) - mu0 * mu0, 0.f) + 1e-5f);
    gk = lng + skc * 8; bk = lnb + skc * 8;
  }
  const __bf16* Bg = Bt + (size_t)(col0 + srow) * K + skc * 8;

  // prefetch registers
  bf16x8 pa0, pa1, pb0, pb1;
  float4 f00, f01, pg0, pg1, pc0, pc1;

  auto prefetch = [&](int kk) {
    if (AMODE == 0) {
      pa0 = *(const bf16x8*)(Ag + kk);
      if (AR2) pa1 = *(const bf16x8*)(Ag + (size_t)64 * K + kk);
    } else {
      f00 = *(const float4*)(Ax0 + kk); f01 = *(const float4*)(Ax0 + kk + 4);
      pg0 = *(const float4*)(gk + kk);  pg1 = *(const float4*)(gk + kk + 4);
      pc0 = *(const float4*)(bk + kk);  pc1 = *(const float4*)(bk + kk + 4);
    }
    pb0 = *(const bf16x8*)(Bg + kk);
    if (BR2) pb1 = *(const bf16x8*)(Bg + (size_t)64 * K + kk);
  };
  auto store_lds = [&](int buf) {
    if (AMODE == 0) {
      *(bf16x8*)&As[buf][wA0] = pa0;
      if (AR2) *(bf16x8*)&As[buf][wA1] = pa1;
    } else {
      *(bf16x8*)&As[buf][wA0] = ln8v(f00, f01, mu0, rs0, pg0, pg1, pc0, pc1);
    }
    *(bf16x8*)&Bs[buf][wA0] = pb0;
    if (BR2) *(bf16x8*)&Bs[buf][wA1] = pb1;
  };

  prefetch(0);
  store_lds(0);
  __syncthreads();

  int cur = 0;
  for (int k0 = 0; k0 < K; k0 += 32) {
    const bool nxt = (k0 + 32 < K);
    if (nxt) prefetch(k0 + 32);       // loads fly during MFMA below
    bf16x8 af[MR], bfr[NR];
#pragma unroll
    for (int m = 0; m < MR; m++) {
      int r = wm * WMS + m * 16 + rm;
      af[m] = *(const bf16x8*)&As[cur][((r * 4 + g4) ^ (r & 7)) * 8];
    }
#pragma unroll
    for (int n = 0; n < NR; n++) {
      int r = wn * WNS + n * 16 + rm;
      bfr[n] = *(const bf16x8*)&Bs[cur][((r * 4 + g4) ^ (r & 7)) * 8];
    }
#pragma unroll
    for (int m = 0; m < MR; m++)
#pragma unroll
      for (int n = 0; n < NR; n++)
        acc[m][n] = __builtin_amdgcn_mfma_f32_16x16x32_bf16(af[m], bfr[n], acc[m][n], 0, 0, 0);
    if (nxt) {
      store_lds(cur ^ 1);             // prev iter's reads of buf^1 were barrier-ordered
      __syncthreads();
    }
    cur ^= 1;
  }

#pragma unroll
  for (int m = 0; m < MR; m++) {
    int row_b = row0 + wm * WMS + m * 16 + g4 * 4;
    float bv[NR];
#pragma unroll
    for (int n = 0; n < NR; n++) bv[n] = BIAS ? bias[col0 + wn * WNS + n * 16 + rm] : 0.f;
#pragma unroll
    for (int r = 0; r < 4; r++) {
      int row = row_b + r;
      float s = 0.f, qq = 0.f;
#pragma unroll
      for (int n = 0; n < NR; n++) {
        int col = col0 + wn * WNS + n * 16 + rm;
        float v = acc[m][n][r] + bv[n];
        if (MODE == 0) {
          if (RELU) v = fmaxf(v, 0.f);
          if (row < M) outb[(size_t)row * N + col] = f2bf(v);
        } else if (MODE == 1) {
          if (row < M) { v += res[(size_t)row * N + col]; outf[(size_t)row * N + col] = v; }
          s += v; qq += v * v;
        } else {
          if (row < M) outf[(size_t)row * N + col] = v;
        }
      }
      if (MODE == 1 && STAT) {
#pragma unroll
        for (int msk = 1; msk < 16; msk <<= 1) { s += __shfl_xor(s, msk); qq += __shfl_xor(qq, msk); }
        if (rm == 0 && row < M) {
          ops[(size_t)row * 8 + (col0 >> 6)] = s;
          opq[(size_t)row * 8 + (col0 >> 6)] = qq;
        }
      }
    }
  }
}

// ---------------- fused masked attention (flash-style) ----------------
__global__ __launch_bounds__(256) void k_attn(const __bf16* __restrict__ qkv,
                                              __bf16* __restrict__ ob)
{
  __shared__ __align__(16) __bf16 Ks[32][72];
  __shared__ __align__(16) __bf16 Vs[64][40];
  __shared__ __align__(16) __bf16 Ps[4][16][40];

  const int tid = threadIdx.x;
  const int lane = tid & 63, w = tid >> 6;
  const int rm = lane & 15, g4 = lane >> 4;
  const int q0 = blockIdx.x * 64;
  const int h = blockIdx.y, b = blockIdx.z;
  const int qw = q0 + w * 16;

  const size_t rsd = 1536;
  const __bf16* qb = qkv + (size_t)b * TT1 * rsd + h * HSZ;
  const __bf16* kb = qb + 512;
  const __bf16* vb = qb + 1024;

  bf16x8 aq[2];
  {
    const __bf16* qp = qb + (size_t)(qw + rm) * rsd + 8 * g4;
    aq[0] = *(const bf16x8*)qp;
    aq[1] = *(const bf16x8*)(qp + 32);
  }

  int ae_[4];
#pragma unroll
  for (int r = 0; r < 4; r++) {
    int qr = qw + g4 * 4 + r;
    ae_[r] = (qr / 6 + 1) * 6;
  }

  float m_[4], l_[4];
  f32x4 accO[4];
  const f32x4 fz = {0.f, 0.f, 0.f, 0.f};
#pragma unroll
  for (int j = 0; j < 4; j++) accO[j] = fz;
#pragma unroll
  for (int r = 0; r < 4; r++) { m_[r] = -1e30f; l_[r] = 0.f; }

  int aemax = ((q0 + 63) / 6 + 1) * 6;
  if (aemax > TT) aemax = TT;
  const int ntile = (aemax + 31) >> 5;

  const int skey = tid >> 3;
  const int shs = (tid & 7) * 8;

  for (int tt = 0; tt <= ntile; ++tt) {
    const bool meta = (tt == ntile);
    const int kt = meta ? TT : tt * 32;

    bf16x8 kv_k = *(const bf16x8*)(kb + (size_t)(kt + skey) * rsd + shs);
    bf16x8 kv_v = *(const bf16x8*)(vb + (size_t)(kt + skey) * rsd + shs);
    __syncthreads();
    *(bf16x8*)&Ks[skey][shs] = kv_k;
#pragma unroll
    for (int j = 0; j < 8; j++) Vs[shs + j][skey] = kv_v[j];
    __syncthreads();

    f32x4 s[2];
#pragma unroll
    for (int nt = 0; nt < 2; nt++) {
      f32x4 a = fz;
      bf16x8 bk0 = *(const bf16x8*)&Ks[nt * 16 + rm][8 * g4];
      bf16x8 bk1 = *(const bf16x8*)&Ks[nt * 16 + rm][32 + 8 * g4];
      a = __builtin_amdgcn_mfma_f32_16x16x32_bf16(aq[0], bk0, a, 0, 0, 0);
      a = __builtin_amdgcn_mfma_f32_16x16x32_bf16(aq[1], bk1, a, 0, 0, 0);
      s[nt] = a;
    }

    float alpha[4];
#pragma unroll
    for (int r = 0; r < 4; r++) {
      float s0 = s[0][r] * SCALE;
      float s1 = s[1][r] * SCALE;
      int col0k = kt + rm;
      int lim = meta ? TT1 : ae_[r];
      if (col0k >= lim) s0 = -1e30f;
      if (col0k + 16 >= lim) s1 = -1e30f;
      float tm = fmaxf(s0, s1);
#pragma unroll
      for (int msk = 1; msk < 16; msk <<= 1) tm = fmaxf(tm, __shfl_xor(tm, msk));
      float mn = fmaxf(m_[r], tm);
      float p0 = __expf(s0 - mn);
      float p1 = __expf(s1 - mn);
      float ts = p0 + p1;
#pragma unroll
      for (int msk = 1; msk < 16; msk <<= 1) ts += __shfl_xor(ts, msk);
      alpha[r] = __expf(m_[r] - mn);
      l_[r] = l_[r] * alpha[r] + ts;
      m_[r] = mn;
      Ps[w][g4 * 4 + r][rm]      = f2bf(p0);
      Ps[w][g4 * 4 + r][rm + 16] = f2bf(p1);
    }
#pragma unroll
    for (int j = 0; j < 4; j++)
#pragma unroll
      for (int r = 0; r < 4; r++) accO[j][r] *= alpha[r];
    __syncthreads();

    bf16x8 pa = *(const bf16x8*)&Ps[w][rm][8 * g4];
#pragma unroll
    for (int j = 0; j < 4; j++) {
      bf16x8 bv = *(const bf16x8*)&Vs[j * 16 + rm][8 * g4];
      accO[j] = __builtin_amdgcn_mfma_f32_16x16x32_bf16(pa, bv, accO[j], 0, 0, 0);
    }
  }

#pragma unroll
  for (int r = 0; r < 4; r++) {
    int q = qw + g4 * 4 + r;
    if (q < TT1) {
      float rl = 1.0f / l_[r];
#pragma unroll
      for (int j = 0; j < 4; j++)
        ob[((size_t)b * TT1 + q) * DD + h * HSZ + j * 16 + rm] = f2bf(accO[j][r] * rl);
    }
  }
}

// ---------------- host launcher ----------------
extern "C" void kernel_launch(void* const* d_in, const int* in_sizes, int n_in,
                              void* d_out, int out_size, void* d_ws, size_t ws_size,
                              hipStream_t stream)
{
  const int*   idx   = (const int*)d_in[0];
  const int*   midx  = (const int*)d_in[1];
  const float* tok   = (const float*)d_in[2];
  const float* metae = (const float*)d_in[3];
  const float* Wq    = (const float*)d_in[4];
  const float* Wk    = (const float*)d_in[5];
  const float* Wv    = (const float*)d_in[6];
  const float* Wo    = (const float*)d_in[7];
  const float* bo    = (const float*)d_in[8];
  const float* W1    = (const float*)d_in[9];
  const float* b1    = (const float*)d_in[10];
  const float* W2    = (const float*)d_in[11];
  const float* b2    = (const float*)d_in[12];
  const float* ln1g  = (const float*)d_in[13];
  const float* ln1b  = (const float*)d_in[14];
  const float* ln2g  = (const float*)d_in[15];
  const float* ln2b  = (const float*)d_in[16];
  const float* lnfg  = (const float*)d_in[17];
  const float* lnfb  = (const float*)d_in[18];
  const float* Wlm   = (const float*)d_in[19];
  const float* blm   = (const float*)d_in[20];
  float* out = (float*)d_out;

  char* p = (char*)d_ws;
  auto alloc = [&](size_t bytes) { void* r = (void*)p; p += (bytes + 255) & ~(size_t)255; return r; };
  float*  x     = (float*)alloc((size_t)MPAD * 512 * 4);
  float*  ps_   = (float*)alloc((size_t)MPAD * 8 * 4);
  float*  pq_   = (float*)alloc((size_t)MPAD * 8 * 4);
  __bf16* qkv   = (__bf16*)alloc((size_t)MPAD * 1536 * 2);
  __bf16* obuf  = (__bf16*)alloc((size_t)MPAD * 512 * 2);
  __bf16* f1    = (__bf16*)alloc((size_t)MPAD * 2048 * 2);
  __bf16* xf    = (__bf16*)alloc((size_t)2048 * 512 * 2);
  __bf16* wqkvb = (__bf16*)alloc((size_t)6 * 1536 * 512 * 2);
  __bf16* wob   = (__bf16*)alloc((size_t)6 * 512 * 512 * 2);
  __bf16* w1b   = (__bf16*)alloc((size_t)6 * 2048 * 512 * 2);
  __bf16* w2b   = (__bf16*)alloc((size_t)6 * 512 * 2048 * 2);
  __bf16* wlmb  = (__bf16*)alloc((size_t)NVOCAB * 512 * 2);
  (void)in_sizes; (void)n_in; (void)out_size; (void)ws_size;

  dim3 tcb(32, 8);
  k_tcvt<<<dim3(2, 16, 48), tcb, 0, stream>>>(Wq, wqkvb,          512, 64,   32768LL,  786432LL, 32768LL, 8);
  k_tcvt<<<dim3(2, 16, 48), tcb, 0, stream>>>(Wk, wqkvb + 262144, 512, 64,   32768LL,  786432LL, 32768LL, 8);
  k_tcvt<<<dim3(2, 16, 48), tcb, 0, stream>>>(Wv, wqkvb + 524288, 512, 64,   32768LL,  786432LL, 32768LL, 8);
  k_tcvt<<<dim3(16, 16, 6), tcb, 0, stream>>>(Wo, wob,  512, 512,  262144LL,  262144LL, 0LL, 1);
  k_tcvt<<<dim3(64, 16, 6), tcb, 0, stream>>>(W1, w1b,  512, 2048, 1048576LL, 1048576LL, 0LL, 1);
  k_tcvt<<<dim3(16, 64, 6), tcb, 0, stream>>>(W2, w2b,  2048, 512, 1048576LL, 1048576LL, 0LL, 1);
  k_tcvt<<<dim3(1000, 16, 1), tcb, 0, stream>>>(Wlm, wlmb, 512, 32000, 0LL, 0LL, 0LL, 1);

  k_embed<<<dim3(MROWS), dim3(128), 0, stream>>>(idx, midx, tok, metae, x, ps_, pq_);

  for (int l = 0; l < LL; ++l) {
    // QKV projection with fused ln1 (64x128 tiles, 408 blocks)
    k_gemm<0, false, false, 1, 64, 128, 2, false><<<dim3(34, 12), 256, 0, stream>>>(
        nullptr, x, ps_, pq_, ln1g + l * 512, ln1b + l * 512,
        wqkvb + (size_t)l * 786432, nullptr, nullptr, nullptr, qkv,
        nullptr, nullptr, MROWS, 1536, 512);
    k_attn<<<dim3(17, 8, 2), 256, 0, stream>>>(qkv, obuf);
    // Wo projection + residual + LN partials (64x64 tiles, 272 blocks)
    k_gemm<1, false, true, 0, 64, 64, 4, true><<<dim3(34, 8), 256, 0, stream>>>(
        obuf, nullptr, nullptr, nullptr, nullptr, nullptr,
        wob + (size_t)l * 262144, bo + l * 512, x, x, nullptr,
        ps_, pq_, MROWS, 512, 512);
    // FFN1 with fused ln2 (64x128 tiles, 544 blocks)
    k_gemm<0, true, true, 1, 64, 128, 2, false><<<dim3(34, 16), 256, 0, stream>>>(
        nullptr, x, ps_, pq_, ln2g + l * 512, ln2b + l * 512,
        w1b + (size_t)l * 1048576, b1 + l * 2048, nullptr, nullptr, f1,
        nullptr, nullptr, MROWS, 2048, 512);
    // FFN2 + residual + LN partials (64x64 tiles, 272 blocks)
    k_gemm<1, false, true, 0, 64, 64, 4, true><<<dim3(34, 8), 256, 0, stream>>>(
        f1, nullptr, nullptr, nullptr, nullptr, nullptr,
        w2b + (size_t)l * 1048576, b2 + l * 512, x, x, nullptr,
        ps_, pq_, MROWS, 512, 2048);
  }

  // final LN -> compact bf16 rows, then LM head (128x128 tiles, 4000 blocks)
  k_lnp<<<dim3(512), dim3(64, 4), 0, stream>>>(x, ps_, pq_, lnfg, lnfb, xf);
  k_gemm<2, false, true, 0, 128, 128, 2, false><<<dim3(16, 250), 256, 0, stream>>>(
      xf, nullptr, nullptr, nullptr, nullptr, nullptr,
      wlmb, blm, nullptr, out, nullptr, nullptr, nullptr, 2048, NVOCAB, 512);
}

// Round 5
// 994.688 us; speedup vs baseline: 1.3956x; 1.1345x over previous
//
#include <hip/hip_runtime.h>
#include <hip/hip_bf16.h>
#include <math.h>

// ---------------- problem constants ----------------
#define TT     1024      // T
#define METAN  6
#define TT1    1030      // T + META
#define BB     2
#define DD     512
#define HH     8
#define HSZ    64
#define LL     6
#define NVOCAB 32000
#define MROWS  2060      // B*T1
#define MPAD   2176      // 34 * 64
#define SCALE  0.044194173824159216f   // 512^-0.5

typedef float  f32x4  __attribute__((ext_vector_type(4)));
typedef __bf16 bf16x8 __attribute__((ext_vector_type(8)));

__device__ __forceinline__ __bf16 f2bf(float f) { return (__bf16)f; }  // native RNE cvt

__device__ __forceinline__ void glds16(const __bf16* g, const __bf16* l) {
  __builtin_amdgcn_global_load_lds(
      (const __attribute__((address_space(1))) unsigned int*)g,
      (__attribute__((address_space(3))) unsigned int*)l, 16, 0, 0);
}

// normalize 8 fp32 (register form) -> bf16x8
__device__ __forceinline__ bf16x8 ln8v(float4 v0, float4 v1, float mu, float rs,
                                       float4 g0, float4 g1, float4 b0, float4 b1) {
  float vv[8] = {v0.x, v0.y, v0.z, v0.w, v1.x, v1.y, v1.z, v1.w};
  float gg[8] = {g0.x, g0.y, g0.z, g0.w, g1.x, g1.y, g1.z, g1.w};
  float bb[8] = {b0.x, b0.y, b0.z, b0.w, b1.x, b1.y, b1.z, b1.w};
  bf16x8 r;
#pragma unroll
  for (int j = 0; j < 8; j++) r[j] = f2bf((vv[j] - mu) * rs * gg[j] + bb[j]);
  return r;
}
__device__ __forceinline__ bf16x8 ln8(const float* __restrict__ xp, float mu, float rs,
                                      const float* __restrict__ g, const float* __restrict__ b) {
  return ln8v(*(const float4*)xp, *(const float4*)(xp + 4), mu, rs,
              *(const float4*)g, *(const float4*)(g + 4),
              *(const float4*)b, *(const float4*)(b + 4));
}

// ---------------- embedding + positional encoding + LN partials ----------------
__global__ void k_embed(const int* __restrict__ idx, const int* __restrict__ midx,
                        const float* __restrict__ tok, const float* __restrict__ met,
                        float* __restrict__ x, float* __restrict__ ps, float* __restrict__ pq)
{
  int row = blockIdx.x;
  int b = row / TT1, t = row - b * TT1;
  int d0 = threadIdx.x * 4;
  float v[4];
  if (t < TT) {
    const float* e = tok + (size_t)idx[b * TT + t] * DD;
    float pos = (float)(t / 6);
#pragma unroll
    for (int j = 0; j < 4; j += 2) {
      int i = (d0 + j) >> 1;
      float dv = expf((float)i * (-2.0f * 9.210340371976184f / 512.0f));
      float ang = pos * dv;
      v[j]     = e[d0 + j]     + sinf(ang);
      v[j + 1] = e[d0 + j + 1] + cosf(ang);
    }
  } else {
    const float* e = met + (size_t)midx[b * METAN + (t - TT)] * DD;
#pragma unroll
    for (int j = 0; j < 4; j++) v[j] = e[d0 + j];
  }
  *(float4*)&x[(size_t)row * DD + d0] = *(float4*)v;
  float s = v[0] + v[1] + v[2] + v[3];
  float q = v[0]*v[0] + v[1]*v[1] + v[2]*v[2] + v[3]*v[3];
#pragma unroll
  for (int msk = 1; msk < 16; msk <<= 1) { s += __shfl_xor(s, msk); q += __shfl_xor(q, msk); }
  if ((threadIdx.x & 15) == 0) {
    ps[(size_t)row * 8 + (threadIdx.x >> 4)] = s;
    pq[(size_t)row * 8 + (threadIdx.x >> 4)] = q;
  }
}

// ---------------- final LN -> compact bf16 rows for LM head ----------------
__global__ void k_lnp(const float* __restrict__ x, const float* __restrict__ ps,
                      const float* __restrict__ pq, const float* __restrict__ g,
                      const float* __restrict__ b, __bf16* __restrict__ xf)
{
  int row = blockIdx.x * 4 + threadIdx.y;
  int sr = (row >> 10) * TT1 + (row & 1023);
  int lane = threadIdx.x;
  float s = 0.f, q = 0.f;
#pragma unroll
  for (int j = 0; j < 8; j++) { s += ps[(size_t)sr * 8 + j]; q += pq[(size_t)sr * 8 + j]; }
  float mu = s * (1.0f / 512.0f);
  float rs = rsqrtf(fmaxf(q * (1.0f / 512.0f) - mu * mu, 0.f) + 1e-5f);
  bf16x8 o = ln8(&x[(size_t)sr * DD + lane * 8], mu, rs, &g[lane * 8], &b[lane * 8]);
  *(bf16x8*)&xf[(size_t)row * DD + lane * 8] = o;
}

// ---------------- merged transpose + fp32->bf16 weight conversion (7 jobs, 1 dispatch) ----------------
__global__ void k_tcvt7(const float* __restrict__ Wq, const float* __restrict__ Wk,
                        const float* __restrict__ Wv, const float* __restrict__ Wo,
                        const float* __restrict__ W1, const float* __restrict__ W2,
                        const float* __restrict__ Wlm,
                        __bf16* __restrict__ wqkvb, __bf16* __restrict__ wob,
                        __bf16* __restrict__ w1b, __bf16* __restrict__ w2b,
                        __bf16* __restrict__ wlmb)
{
  __shared__ float t[32][33];
  int bid = blockIdx.x;
  const float* in; __bf16* out;
  int gx, gy, R, C, lo_cnt, local;
  long long in_bs, bs_hi, bs_lo;
  if (bid < 4608) {          // Wq/Wk/Wv -> fused qkv weight, [h] batches
    int job = bid / 1536; local = bid - job * 1536;
    in = job == 0 ? Wq : (job == 1 ? Wk : Wv);
    out = wqkvb + (size_t)job * 262144;
    gx = 2; gy = 16; R = 512; C = 64; in_bs = 32768; bs_hi = 786432; bs_lo = 32768; lo_cnt = 8;
  } else if (bid < 6144) {
    local = bid - 4608; in = Wo; out = wob;
    gx = 16; gy = 16; R = 512; C = 512; in_bs = 262144; bs_hi = 262144; bs_lo = 0; lo_cnt = 1;
  } else if (bid < 12288) {
    local = bid - 6144; in = W1; out = w1b;
    gx = 64; gy = 16; R = 512; C = 2048; in_bs = 1048576; bs_hi = 1048576; bs_lo = 0; lo_cnt = 1;
  } else if (bid < 18432) {
    local = bid - 12288; in = W2; out = w2b;
    gx = 16; gy = 64; R = 2048; C = 512; in_bs = 1048576; bs_hi = 1048576; bs_lo = 0; lo_cnt = 1;
  } else {
    local = bid - 18432; in = Wlm; out = wlmb;
    gx = 1000; gy = 16; R = 512; C = 32000; in_bs = 0; bs_hi = 0; bs_lo = 0; lo_cnt = 1;
  }
  int bx = local % gx; int tmp = local / gx; int by = tmp % gy; int bz = tmp / gy;
  const float* ib = in + (long long)bz * in_bs;
  __bf16* ob = out + (long long)(bz / lo_cnt) * bs_hi + (long long)(bz % lo_cnt) * bs_lo;
  int tx = threadIdx.x & 31, ty = threadIdx.x >> 5;
  int c = bx * 32 + tx;
  for (int j = ty; j < 32; j += 8)
    t[j][tx] = ib[(size_t)(by * 32 + j) * C + c];
  __syncthreads();
  int r = by * 32 + tx;
  for (int j = ty; j < 32; j += 8)
    ob[(size_t)(bx * 32 + j) * R + r] = f2bf(t[tx][j]);
}

// ---------------- generic bf16 GEMM: BK=64, global_load_lds staging, dbuf LDS ----------------
// Tile MT x NT, 4 waves as WM x (4/WM). LDS layout: row r's 8 chunks (8 bf16 each)
// stored at chunk r*8 + (j ^ (r&7))  [2-way-conflict-free ds_read_b128].
// AMODE 0: A bf16 [.][K] staged via global_load_lds with inverse-swizzled source.
// AMODE 1: A = layernorm(Ax fp32 row) computed in regs, ds_written swizzled (MT=64).
// MODE 0: outb = bf16(acc (+bias) (ReLU));  MODE 1: outf = res+acc+bias (+STAT, WM=4, NT=64);
// MODE 2: outf = acc + bias, LDS-transposed dwordx4 stores (rows all valid).
template <int MODE, bool RELU, bool BIAS, int AMODE, int MT, int NT, int WM, bool STAT>
__global__ __launch_bounds__(256, 3) void k_gemm(
    const __bf16* __restrict__ A, const float* __restrict__ Ax,
    const float* __restrict__ ps, const float* __restrict__ pq,
    const float* __restrict__ lng, const float* __restrict__ lnb,
    const __bf16* __restrict__ Bt, const float* __restrict__ bias,
    const float* __restrict__ res,
    float* __restrict__ outf, __bf16* __restrict__ outb,
    float* __restrict__ ops, float* __restrict__ opq,
    int M, int N, int K)
{
  constexpr int WN  = 4 / WM;
  constexpr int WMS = MT / WM;
  constexpr int WNS = NT / WN;
  constexpr int MR  = WMS / 16;
  constexpr int NR  = WNS / 16;
  constexpr int RA  = MT / 32;       // glds rounds (256 chunks each) per A buffer
  constexpr int RB  = NT / 32;

  __shared__ __align__(16) unsigned char smem[(MT + NT) * 256];  // 2 bufs (A+B), 64-K deep
  __bf16* const Asm = (__bf16*)smem;                 // [2][MT*64]
  __bf16* const Bsm = (__bf16*)smem + 2 * MT * 64;   // [2][NT*64]

  const int tid = threadIdx.x;
  const int lane = tid & 63, w = tid >> 6;
  const int wm = (WN == 1) ? w : (w >> 1);
  const int wn = (WN == 1) ? 0 : (w & 1);
  const int rm = lane & 15, g4 = lane >> 4;

  // XCD-bijective swizzle (row-tile fastest inside each XCD chunk)
  const int nbx = gridDim.x;
  int flat = blockIdx.y * nbx + blockIdx.x;
  {
    const int nwg = nbx * gridDim.y;
    const int q = nwg >> 3, rr = nwg & 7;
    const int xcd = flat & 7, ii = flat >> 3;
    flat = (xcd < rr ? xcd * (q + 1) : rr * (q + 1) + (xcd - rr) * q) + ii;
  }
  const int row0 = (flat % nbx) * MT;
  const int col0 = (flat / nbx) * NT;

  f32x4 acc[MR][NR];
  const f32x4 fz = {0.f, 0.f, 0.f, 0.f};
#pragma unroll
  for (int i = 0; i < MR; i++)
#pragma unroll
    for (int j = 0; j < NR; j++) acc[i][j] = fz;

  // ---- staging source pointers (inverse-swizzled per-lane addresses) ----
  const __bf16* bSrc[RB];
#pragma unroll
  for (int i = 0; i < RB; i++) {
    int c = i * 256 + tid; int r = c >> 3; int j = (c & 7) ^ (r & 7);
    bSrc[i] = Bt + (size_t)(col0 + r) * K + j * 8;
  }
  const __bf16* aSrc[RA];
  const float *Ax0 = nullptr, *gk = nullptr, *bk = nullptr;
  float mu0 = 0.f, rs0 = 0.f;
  int oA0 = 0, oA1 = 0;
  if (AMODE == 0) {
#pragma unroll
    for (int i = 0; i < RA; i++) {
      int c = i * 256 + tid; int r = c >> 3; int j = (c & 7) ^ (r & 7);
      aSrc[i] = A + (size_t)(row0 + r) * K + j * 8;
    }
  } else {
    int srow = tid >> 2, skc = tid & 3;
    int sa0 = row0 + srow;
    Ax0 = Ax + (size_t)sa0 * DD + skc * 8;
    float s0 = 0.f, q0 = 0.f;
#pragma unroll
    for (int j = 0; j < 8; j++) { s0 += ps[(size_t)sa0 * 8 + j]; q0 += pq[(size_t)sa0 * 8 + j]; }
    mu0 = s0 * (1.0f / 512.0f);
    rs0 = rsqrtf(fmaxf(q0 * (1.0f / 512.0f) - mu0 * mu0, 0.f) + 1e-5f);
    gk = lng + skc * 8; bk = lnb + skc * 8;
    oA0 = (srow * 8 + (skc ^ (srow & 7))) * 8;
    oA1 = (srow * 8 + ((skc + 4) ^ (srow & 7))) * 8;
  }

  float4 xa0, xa1, xb0, xb1, ga0, ga1, gb0, gb1, ca0, ca1, cb0, cb1;
  auto loadA1 = [&](int k0) {            // LN-fused A: fp32 loads into regs
    xa0 = *(const float4*)(Ax0 + k0);      xa1 = *(const float4*)(Ax0 + k0 + 4);
    xb0 = *(const float4*)(Ax0 + k0 + 32); xb1 = *(const float4*)(Ax0 + k0 + 36);
    ga0 = *(const float4*)(gk + k0);       ga1 = *(const float4*)(gk + k0 + 4);
    gb0 = *(const float4*)(gk + k0 + 32);  gb1 = *(const float4*)(gk + k0 + 36);
    ca0 = *(const float4*)(bk + k0);       ca1 = *(const float4*)(bk + k0 + 4);
    cb0 = *(const float4*)(bk + k0 + 32);  cb1 = *(const float4*)(bk + k0 + 36);
  };
  auto writeA1 = [&](int buf) {
    *(bf16x8*)(Asm + buf * MT * 64 + oA0) = ln8v(xa0, xa1, mu0, rs0, ga0, ga1, ca0, ca1);
    *(bf16x8*)(Asm + buf * MT * 64 + oA1) = ln8v(xb0, xb1, mu0, rs0, gb0, gb1, cb0, cb1);
  };
  auto stageB = [&](int buf, int k0) {
#pragma unroll
    for (int i = 0; i < RB; i++)
      glds16(bSrc[i] + k0, Bsm + buf * NT * 64 + (i * 256 + w * 64) * 8);
  };
  auto stageA0 = [&](int buf, int k0) {
#pragma unroll
    for (int i = 0; i < RA; i++)
      glds16(aSrc[i] + k0, Asm + buf * MT * 64 + (i * 256 + w * 64) * 8);
  };

  // ---- prologue ----
  stageB(0, 0);
  if (AMODE == 0) stageA0(0, 0);
  else { loadA1(0); writeA1(0); }
  __syncthreads();

  int cur = 0;
  for (int k0 = 0; k0 < K; k0 += 64) {
    const bool nxt = (k0 + 64 < K);
    if (nxt) {
      stageB(cur ^ 1, k0 + 64);
      if (AMODE == 0) stageA0(cur ^ 1, k0 + 64);
      else loadA1(k0 + 64);
    }
    const __bf16* Acur = Asm + cur * MT * 64;
    const __bf16* Bcur = Bsm + cur * NT * 64;
    bf16x8 af[MR][2], bf[NR][2];
#pragma unroll
    for (int m = 0; m < MR; m++) {
      int r = wm * WMS + m * 16 + rm;
      int c0 = r * 8 + (g4 ^ (r & 7));
      af[m][0] = *(const bf16x8*)(Acur + c0 * 8);
      af[m][1] = *(const bf16x8*)(Acur + (c0 ^ 4) * 8);
    }
#pragma unroll
    for (int n = 0; n < NR; n++) {
      int r = wn * WNS + n * 16 + rm;
      int c0 = r * 8 + (g4 ^ (r & 7));
      bf[n][0] = *(const bf16x8*)(Bcur + c0 * 8);
      bf[n][1] = *(const bf16x8*)(Bcur + (c0 ^ 4) * 8);
    }
#pragma unroll
    for (int t = 0; t < 2; t++)
#pragma unroll
      for (int m = 0; m < MR; m++)
#pragma unroll
        for (int n = 0; n < NR; n++)
          acc[m][n] = __builtin_amdgcn_mfma_f32_16x16x32_bf16(af[m][t], bf[n][t], acc[m][n], 0, 0, 0);
    if (nxt) {
      if (AMODE == 1) writeA1(cur ^ 1);
      __syncthreads();
    }
    cur ^= 1;
  }

  // ---- epilogue ----
  if (MODE == 2) {
    // transpose through LDS -> dwordx4 coalesced stores (all rows valid)
    __syncthreads();
    float* T = (float*)smem;
    const int wbase = w * (32 * 68);
#pragma unroll
    for (int m = 0; m < MR; m++)
#pragma unroll
      for (int n = 0; n < NR; n++) {
        float bvv = BIAS ? bias[col0 + wn * WNS + n * 16 + rm] : 0.f;
#pragma unroll
        for (int r = 0; r < 4; r++)
          T[wbase + (m * 16 + g4 * 4 + r) * 68 + n * 16 + rm] = acc[m][n][r] + bvv;
      }
#pragma unroll
    for (int i = 0; i < 8; i++) {
      int rloc = (lane >> 4) + i * 4;
      int cg = lane & 15;
      float4 v = *(float4*)&T[wbase + rloc * 68 + cg * 4];
      *(float4*)&outf[(size_t)(row0 + wm * WMS + rloc) * N + col0 + wn * WNS + cg * 4] = v;
    }
  } else {
#pragma unroll
    for (int m = 0; m < MR; m++) {
      int row_b = row0 + wm * WMS + m * 16 + g4 * 4;
      float bv[NR];
#pragma unroll
      for (int n = 0; n < NR; n++) bv[n] = BIAS ? bias[col0 + wn * WNS + n * 16 + rm] : 0.f;
#pragma unroll
      for (int r = 0; r < 4; r++) {
        int row = row_b + r;
        float s = 0.f, qq = 0.f;
#pragma unroll
        for (int n = 0; n < NR; n++) {
          int col = col0 + wn * WNS + n * 16 + rm;
          float v = acc[m][n][r] + bv[n];
          if (MODE == 0) {
            if (RELU) v = fmaxf(v, 0.f);
            if (row < M) outb[(size_t)row * N + col] = f2bf(v);
          } else {
            if (row < M) { v += res[(size_t)row * N + col]; outf[(size_t)row * N + col] = v; }
            s += v; qq += v * v;
          }
        }
        if (MODE == 1 && STAT) {
#pragma unroll
          for (int msk = 1; msk < 16; msk <<= 1) { s += __shfl_xor(s, msk); qq += __shfl_xor(qq, msk); }
          if (rm == 0 && row < M) {
            ops[(size_t)row * 8 + (col0 >> 6)] = s;
            opq[(size_t)row * 8 + (col0 >> 6)] = qq;
          }
        }
      }
    }
  }
}

// ---------------- fused masked attention (flash-style) ----------------
__global__ __launch_bounds__(256) void k_attn(const __bf16* __restrict__ qkv,
                                              __bf16* __restrict__ ob)
{
  __shared__ __align__(16) __bf16 Ks[32][72];
  __shared__ __align__(16) __bf16 Vs[64][40];
  __shared__ __align__(16) __bf16 Ps[4][16][40];

  const int tid = threadIdx.x;
  const int lane = tid & 63, w = tid >> 6;
  const int rm = lane & 15, g4 = lane >> 4;
  const int q0 = blockIdx.x * 64;
  const int h = blockIdx.y, b = blockIdx.z;
  const int qw = q0 + w * 16;

  const size_t rsd = 1536;
  const __bf16* qb = qkv + (size_t)b * TT1 * rsd + h * HSZ;
  const __bf16* kb = qb + 512;
  const __bf16* vb = qb + 1024;

  bf16x8 aq[2];
  {
    const __bf16* qp = qb + (size_t)(qw + rm) * rsd + 8 * g4;
    aq[0] = *(const bf16x8*)qp;
    aq[1] = *(const bf16x8*)(qp + 32);
  }

  int ae_[4];
#pragma unroll
  for (int r = 0; r < 4; r++) {
    int qr = qw + g4 * 4 + r;
    ae_[r] = (qr / 6 + 1) * 6;
  }

  float m_[4], l_[4];
  f32x4 accO[4];
  const f32x4 fz = {0.f, 0.f, 0.f, 0.f};
#pragma unroll
  for (int j = 0; j < 4; j++) accO[j] = fz;
#pragma unroll
  for (int r = 0; r < 4; r++) { m_[r] = -1e30f; l_[r] = 0.f; }

  int aemax = ((q0 + 63) / 6 + 1) * 6;
  if (aemax > TT) aemax = TT;
  const int ntile = (aemax + 31) >> 5;

  const int skey = tid >> 3;
  const int shs = (tid & 7) * 8;

  for (int tt = 0; tt <= ntile; ++tt) {
    const bool meta = (tt == ntile);
    const int kt = meta ? TT : tt * 32;

    bf16x8 kv_k = *(const bf16x8*)(kb + (size_t)(kt + skey) * rsd + shs);
    bf16x8 kv_v = *(const bf16x8*)(vb + (size_t)(kt + skey) * rsd + shs);
    __syncthreads();
    *(bf16x8*)&Ks[skey][shs] = kv_k;
#pragma unroll
    for (int j = 0; j < 8; j++) Vs[shs + j][skey] = kv_v[j];
    __syncthreads();

    f32x4 s[2];
#pragma unroll
    for (int nt = 0; nt < 2; nt++) {
      f32x4 a = fz;
      bf16x8 bk0 = *(const bf16x8*)&Ks[nt * 16 + rm][8 * g4];
      bf16x8 bk1 = *(const bf16x8*)&Ks[nt * 16 + rm][32 + 8 * g4];
      a = __builtin_amdgcn_mfma_f32_16x16x32_bf16(aq[0], bk0, a, 0, 0, 0);
      a = __builtin_amdgcn_mfma_f32_16x16x32_bf16(aq[1], bk1, a, 0, 0, 0);
      s[nt] = a;
    }

    float alpha[4];
#pragma unroll
    for (int r = 0; r < 4; r++) {
      float s0 = s[0][r] * SCALE;
      float s1 = s[1][r] * SCALE;
      int col0k = kt + rm;
      int lim = meta ? TT1 : ae_[r];
      if (col0k >= lim) s0 = -1e30f;
      if (col0k + 16 >= lim) s1 = -1e30f;
      float tm = fmaxf(s0, s1);
#pragma unroll
      for (int msk = 1; msk < 16; msk <<= 1) tm = fmaxf(tm, __shfl_xor(tm, msk));
      float mn = fmaxf(m_[r], tm);
      float p0 = __expf(s0 - mn);
      float p1 = __expf(s1 - mn);
      float ts = p0 + p1;
#pragma unroll
      for (int msk = 1; msk < 16; msk <<= 1) ts += __shfl_xor(ts, msk);
      alpha[r] = __expf(m_[r] - mn);
      l_[r] = l_[r] * alpha[r] + ts;
      m_[r] = mn;
      Ps[w][g4 * 4 + r][rm]      = f2bf(p0);
      Ps[w][g4 * 4 + r][rm + 16] = f2bf(p1);
    }
#pragma unroll
    for (int j = 0; j < 4; j++)
#pragma unroll
      for (int r = 0; r < 4; r++) accO[j][r] *= alpha[r];
    __syncthreads();

    bf16x8 pa = *(const bf16x8*)&Ps[w][rm][8 * g4];
#pragma unroll
    for (int j = 0; j < 4; j++) {
      bf16x8 bv = *(const bf16x8*)&Vs[j * 16 + rm][8 * g4];
      accO[j] = __builtin_amdgcn_mfma_f32_16x16x32_bf16(pa, bv, accO[j], 0, 0, 0);
    }
  }

#pragma unroll
  for (int r = 0; r < 4; r++) {
    int q = qw + g4 * 4 + r;
    if (q < TT1) {
      float rl = 1.0f / l_[r];
#pragma unroll
      for (int j = 0; j < 4; j++)
        ob[((size_t)b * TT1 + q) * DD + h * HSZ + j * 16 + rm] = f2bf(accO[j][r] * rl);
    }
  }
}

// ---------------- host launcher ----------------
extern "C" void kernel_launch(void* const* d_in, const int* in_sizes, int n_in,
                              void* d_out, int out_size, void* d_ws, size_t ws_size,
                              hipStream_t stream)
{
  const int*   idx   = (const int*)d_in[0];
  const int*   midx  = (const int*)d_in[1];
  const float* tok   = (const float*)d_in[2];
  const float* metae = (const float*)d_in[3];
  const float* Wq    = (const float*)d_in[4];
  const float* Wk    = (const float*)d_in[5];
  const float* Wv    = (const float*)d_in[6];
  const float* Wo    = (const float*)d_in[7];
  const float* bo    = (const float*)d_in[8];
  const float* W1    = (const float*)d_in[9];
  const float* b1    = (const float*)d_in[10];
  const float* W2    = (const float*)d_in[11];
  const float* b2    = (const float*)d_in[12];
  const float* ln1g  = (const float*)d_in[13];
  const float* ln1b  = (const float*)d_in[14];
  const float* ln2g  = (const float*)d_in[15];
  const float* ln2b  = (const float*)d_in[16];
  const float* lnfg  = (const float*)d_in[17];
  const float* lnfb  = (const float*)d_in[18];
  const float* Wlm   = (const float*)d_in[19];
  const float* blm   = (const float*)d_in[20];
  float* out = (float*)d_out;

  char* p = (char*)d_ws;
  auto alloc = [&](size_t bytes) { void* r = (void*)p; p += (bytes + 255) & ~(size_t)255; return r; };
  float*  x     = (float*)alloc((size_t)MPAD * 512 * 4);
  float*  ps_   = (float*)alloc((size_t)MPAD * 8 * 4);
  float*  pq_   = (float*)alloc((size_t)MPAD * 8 * 4);
  __bf16* qkv   = (__bf16*)alloc((size_t)MPAD * 1536 * 2);
  __bf16* obuf  = (__bf16*)alloc((size_t)MPAD * 512 * 2);
  __bf16* f1    = (__bf16*)alloc((size_t)MPAD * 2048 * 2);
  __bf16* xf    = (__bf16*)alloc((size_t)2048 * 512 * 2);
  __bf16* wqkvb = (__bf16*)alloc((size_t)6 * 1536 * 512 * 2);
  __bf16* wob   = (__bf16*)alloc((size_t)6 * 512 * 512 * 2);
  __bf16* w1b   = (__bf16*)alloc((size_t)6 * 2048 * 512 * 2);
  __bf16* w2b   = (__bf16*)alloc((size_t)6 * 512 * 2048 * 2);
  __bf16* wlmb  = (__bf16*)alloc((size_t)NVOCAB * 512 * 2);
  (void)in_sizes; (void)n_in; (void)out_size; (void)ws_size;

  // all 7 weight conversions in one dispatch
  k_tcvt7<<<dim3(34432), 256, 0, stream>>>(Wq, Wk, Wv, Wo, W1, W2, Wlm,
                                           wqkvb, wob, w1b, w2b, wlmb);

  k_embed<<<dim3(MROWS), dim3(128), 0, stream>>>(idx, midx, tok, metae, x, ps_, pq_);

  for (int l = 0; l < LL; ++l) {
    // QKV projection with fused ln1 (64x128 tiles)
    k_gemm<0, false, false, 1, 64, 128, 2, false><<<dim3(34, 12), 256, 0, stream>>>(
        nullptr, x, ps_, pq_, ln1g + l * 512, ln1b + l * 512,
        wqkvb + (size_t)l * 786432, nullptr, nullptr, nullptr, qkv,
        nullptr, nullptr, MROWS, 1536, 512);
    k_attn<<<dim3(17, 8, 2), 256, 0, stream>>>(qkv, obuf);
    // Wo projection + residual + LN partials (64x64 tiles)
    k_gemm<1, false, true, 0, 64, 64, 4, true><<<dim3(34, 8), 256, 0, stream>>>(
        obuf, nullptr, nullptr, nullptr, nullptr, nullptr,
        wob + (size_t)l * 262144, bo + l * 512, x, x, nullptr,
        ps_, pq_, MROWS, 512, 512);
    // FFN1 with fused ln2 (64x128 tiles)
    k_gemm<0, true, true, 1, 64, 128, 2, false><<<dim3(34, 16), 256, 0, stream>>>(
        nullptr, x, ps_, pq_, ln2g + l * 512, ln2b + l * 512,
        w1b + (size_t)l * 1048576, b1 + l * 2048, nullptr, nullptr, f1,
        nullptr, nullptr, MROWS, 2048, 512);
    // FFN2 + residual + LN partials (64x64 tiles)
    k_gemm<1, false, true, 0, 64, 64, 4, true><<<dim3(34, 8), 256, 0, stream>>>(
        f1, nullptr, nullptr, nullptr, nullptr, nullptr,
        w2b + (size_t)l * 1048576, b2 + l * 512, x, x, nullptr,
        ps_, pq_, MROWS, 512, 2048);
  }

  // final LN -> compact bf16 rows, then LM head (64x128 tiles, 8000 blocks)
  k_lnp<<<dim3(512), dim3(64, 4), 0, stream>>>(x, ps_, pq_, lnfg, lnfb, xf);
  k_gemm<2, false, true, 0, 64, 128, 2, false><<<dim3(32, 250), 256, 0, stream>>>(
      xf, nullptr, nullptr, nullptr, nullptr, nullptr,
      wlmb, blm, nullptr, out, nullptr, nullptr, nullptr, 2048, NVOCAB, 512);
}